// Round 6
// baseline (621.224 us; speedup 1.0000x reference)
//
#include <hip/hip_runtime.h>
#include <math.h>

#define B_  2
#define T_  2048
#define C_  1024
#define H_  16
#define S_  16
#define HD_ 64
#define NCH 32
#define CHL 64   /* T_/NCH */

typedef short  short8  __attribute__((ext_vector_type(8)));
typedef unsigned short ushort8 __attribute__((ext_vector_type(8)));
typedef unsigned short ushort4v __attribute__((ext_vector_type(4)));
typedef float  f32x4   __attribute__((ext_vector_type(4)));

__device__ __forceinline__ float softplus_f(float v) {
    return fmaxf(v, 0.f) + log1pf(__expf(-fabsf(v)));
}

__device__ __forceinline__ unsigned short f2bf(float x) {
    unsigned u = __float_as_uint(x);
    u += 0x7fffu + ((u >> 16) & 1u);
    return (unsigned short)(u >> 16);
}

// ---------------------------------------------------------------------------
// cast fp32 -> bf16 (vectorized), n4 = n/4
// ---------------------------------------------------------------------------
__global__ __launch_bounds__(256) void cast_bf16(const float* __restrict__ in,
                                                 unsigned short* __restrict__ out,
                                                 int n4)
{
    int i = blockIdx.x * 256 + threadIdx.x;
    if (i >= n4) return;
    float4 v = ((const float4*)in)[i];
    ushort4v o = {f2bf(v.x), f2bf(v.y), f2bf(v.z), f2bf(v.w)};
    ((ushort4v*)out)[i] = o;
}

// ---------------------------------------------------------------------------
// transpose-cast: W (1024 x 1024 fp32) -> WT (1024 x 1024 bf16, transposed)
// ---------------------------------------------------------------------------
__device__ __forceinline__ void wtrans_body(const float* __restrict__ W,
                                            unsigned short* __restrict__ WT,
                                            int bx, int by, int tid)
{
    __shared__ float t[32][33];
    const int n0 = bx * 32, k0 = by * 32;
    const int tx = tid & 31, ty = tid >> 5;
#pragma unroll
    for (int p = 0; p < 4; ++p)
        t[ty + p * 8][tx] = W[(size_t)(k0 + ty + p * 8) * C_ + n0 + tx];
    __syncthreads();
#pragma unroll
    for (int p = 0; p < 4; ++p)
        WT[(size_t)(n0 + ty + p * 8) * C_ + k0 + tx] = f2bf(t[tx][ty + p * 8]);
}

__global__ __launch_bounds__(256) void wtrans(const float* __restrict__ W,
                                              unsigned short* __restrict__ WT)
{
    wtrans_body(W, WT, blockIdx.x, blockIdx.y, threadIdx.x);
}

// z: 0 Wx->Astack, 1 Wd->Astack+1024 rows, 2 Wq->Wqkv, 3 Wk->+1024, 4 Wv->+2048
__global__ __launch_bounds__(256) void wtrans_multi(
    const float* __restrict__ Wx, const float* __restrict__ Wd,
    const float* __restrict__ Wq, const float* __restrict__ Wk,
    const float* __restrict__ Wv,
    unsigned short* __restrict__ Astack, unsigned short* __restrict__ Wqkv)
{
    const float* src;
    unsigned short* dst;
    switch (blockIdx.z) {
        case 0: src = Wx; dst = Astack; break;
        case 1: src = Wd; dst = Astack + (size_t)1024 * 1024; break;
        case 2: src = Wq; dst = Wqkv; break;
        case 3: src = Wk; dst = Wqkv + (size_t)1024 * 1024; break;
        default: src = Wv; dst = Wqkv + (size_t)2048 * 1024; break;
    }
    wtrans_body(src, dst, blockIdx.x, blockIdx.y, threadIdx.x);
}

// ---------------------------------------------------------------------------
// misc prep: WB/WC transposed into Astack rows 2048..2079 + stacked biases
// ---------------------------------------------------------------------------
__global__ __launch_bounds__(256) void prep_misc(
    const float* __restrict__ WB, const float* __restrict__ WC,
    const float* __restrict__ bx, const float* __restrict__ bd,
    const float* __restrict__ bq, const float* __restrict__ bk,
    const float* __restrict__ bv,
    unsigned short* __restrict__ Astack, float* __restrict__ biasPD,
    float* __restrict__ biasQKV)
{
    int gid = blockIdx.x * 256 + threadIdx.x;
    if (gid < 32768) {
        int w = gid >> 14, rem = gid & 16383;
        int s = rem >> 10, k = rem & 1023;
        const float* src = w ? WC : WB;
        Astack[(size_t)(2048 + w * 16 + s) * 1024 + k] = f2bf(src[k * 16 + s]);
    } else {
        int id = gid - 32768;
        if (id < 2176) {
            biasPD[id] = id < 1024 ? bx[id] : (id < 2048 ? bd[id - 1024] : 0.f);
        } else {
            int id2 = id - 2176;
            if (id2 < 3072)
                biasQKV[id2] = id2 < 1024 ? bq[id2]
                             : (id2 < 2048 ? bk[id2 - 1024] : bv[id2 - 2048]);
        }
    }
}

// ---------------------------------------------------------------------------
// bf16 MFMA GEMM: acc = A(M x K) @ B(N x K)^T, both lda-strided K-major bf16.
// 128x128 tile, BK=32, 256 threads = 4 waves (2x2 of 64x64), dbuf LDS via
// global_load_lds width=16.
// mode 0: split-K partial fp32; z=0 -> outv, z=1 -> out2 (no bias)
// mode 1: fused projT. rows: [0,1024) xbaseT, [1024,2048) deltaT(softplus),
//         [2048,2064) BmT, [2064,2080) CmT; cols = b*T+t. bias = biasPD[row].
// mode 2: fused QKV. cols: [0,1024) Q heads (outv), [1024,2048) K heads (out2),
//         [2048,3072) V transposed (out3). bias = biasQKV[col].
// ---------------------------------------------------------------------------
__global__ __launch_bounds__(256) void gemm_mfma(
    const unsigned short* __restrict__ A, const unsigned short* __restrict__ Bm,
    const float* __restrict__ bias,
    void* __restrict__ outv, void* __restrict__ out2,
    void* __restrict__ out3, void* __restrict__ out4,
    int M, int N, int K, int lda, int mode)
{
    __shared__ __align__(16) unsigned short As[2][4096];
    __shared__ __align__(16) unsigned short Bs[2][4096];

    const int tid = threadIdx.x;
    const int w = tid >> 6, lane = tid & 63;
    const int lq = lane & 15, lg = lane >> 4;
    const int wm = w >> 1, wn = w & 1;
    const int mBase = blockIdx.y * 128, nBase = blockIdx.x * 128;

    A  += (size_t)blockIdx.z * K;     // split-K column offset (z=0 for others)
    Bm += (size_t)blockIdx.z * K;

    const int c0 = tid, c1 = tid + 256;
    const int rA0 = ((c0 >> 6) << 4) + (c0 & 15), kO0 = ((c0 >> 4) & 3) << 3;
    const int rA1 = ((c1 >> 6) << 4) + (c1 & 15), kO1 = ((c1 >> 4) & 3) << 3;

    f32x4 acc[4][4];
#pragma unroll
    for (int i = 0; i < 4; ++i)
#pragma unroll
        for (int j = 0; j < 4; ++j) acc[i][j] = (f32x4){0.f, 0.f, 0.f, 0.f};

    const unsigned short* ga0 = A  + (size_t)(mBase + rA0) * lda + kO0;
    const unsigned short* ga1 = A  + (size_t)(mBase + rA1) * lda + kO1;
    const unsigned short* gb0 = Bm + (size_t)(nBase + rA0) * lda + kO0;
    const unsigned short* gb1 = Bm + (size_t)(nBase + rA1) * lda + kO1;

    #define LOAD_TILES(k0v, bufv)                                              \
        do {                                                                   \
            __builtin_amdgcn_global_load_lds(                                  \
                (const __attribute__((address_space(1))) void*)(ga0 + (k0v)),  \
                (__attribute__((address_space(3))) void*)&As[bufv][(w * 64) * 8],        16, 0, 0); \
            __builtin_amdgcn_global_load_lds(                                  \
                (const __attribute__((address_space(1))) void*)(ga1 + (k0v)),  \
                (__attribute__((address_space(3))) void*)&As[bufv][(256 + w * 64) * 8],  16, 0, 0); \
            __builtin_amdgcn_global_load_lds(                                  \
                (const __attribute__((address_space(1))) void*)(gb0 + (k0v)),  \
                (__attribute__((address_space(3))) void*)&Bs[bufv][(w * 64) * 8],        16, 0, 0); \
            __builtin_amdgcn_global_load_lds(                                  \
                (const __attribute__((address_space(1))) void*)(gb1 + (k0v)),  \
                (__attribute__((address_space(3))) void*)&Bs[bufv][(256 + w * 64) * 8],  16, 0, 0); \
        } while (0)

    int buf = 0;
    LOAD_TILES(0, 0);
    for (int k0 = 0; k0 < K; k0 += 32) {
        __syncthreads();
        if (k0 + 32 < K) LOAD_TILES(k0 + 32, buf ^ 1);
        short8 a[4], b[4];
#pragma unroll
        for (int i = 0; i < 4; ++i)
            a[i] = *(const short8*)&As[buf][((wm * 4 + i) * 64 + lg * 16 + lq) * 8];
#pragma unroll
        for (int j = 0; j < 4; ++j)
            b[j] = *(const short8*)&Bs[buf][((wn * 4 + j) * 64 + lg * 16 + lq) * 8];
#pragma unroll
        for (int i = 0; i < 4; ++i)
#pragma unroll
            for (int j = 0; j < 4; ++j)
                acc[i][j] = __builtin_amdgcn_mfma_f32_16x16x32_bf16(
                    a[i], b[j], acc[i][j], 0, 0, 0);
        buf ^= 1;
    }
    #undef LOAD_TILES

    if (mode == 0) {
        float* O = blockIdx.z ? (float*)out2 : (float*)outv;
#pragma unroll
        for (int i = 0; i < 4; ++i) {
            int Rb = mBase + wm * 64 + i * 16 + lg * 4;
#pragma unroll
            for (int j = 0; j < 4; ++j) {
                int Cg = nBase + wn * 64 + j * 16 + lq;
#pragma unroll
                for (int r = 0; r < 4; ++r)
                    O[(size_t)(Rb + r) * N + Cg] = acc[i][j][r];
            }
        }
    } else if (mode == 1) {
        float* xbaseT = (float*)outv;
        float* deltaT = (float*)out2;
        float* BmT    = (float*)out3;
        float* CmT    = (float*)out4;
#pragma unroll
        for (int i = 0; i < 4; ++i) {
            int Rb = mBase + wm * 64 + i * 16 + lg * 4;
            if (Rb >= 2080) continue;
            float bb[4];
#pragma unroll
            for (int r = 0; r < 4; ++r) bb[r] = bias[Rb + r];
#pragma unroll
            for (int j = 0; j < 4; ++j) {
                int Cg = nBase + wn * 64 + j * 16 + lq;
                int b = Cg >> 11, t = Cg & (T_ - 1);
#pragma unroll
                for (int r = 0; r < 4; ++r) {
                    int R = Rb + r;
                    float v = acc[i][j][r] + bb[r];
                    if (Rb < 1024) {
                        xbaseT[((size_t)b * C_ + R) * T_ + t] = v;
                    } else if (Rb < 2048) {
                        deltaT[((size_t)b * C_ + (R - 1024)) * T_ + t] =
                            softplus_f(v);
                    } else if (Rb < 2064) {
                        BmT[((size_t)b * S_ + (R - 2048)) * T_ + t] = v;
                    } else {
                        CmT[((size_t)b * S_ + (R - 2064)) * T_ + t] = v;
                    }
                }
            }
        }
    } else { // mode 2: QKV
        unsigned short* Qb  = (unsigned short*)outv;
        unsigned short* Kb  = (unsigned short*)out2;
        unsigned short* VTb = (unsigned short*)out3;
#pragma unroll
        for (int j = 0; j < 4; ++j) {
            int Cg = nBase + wn * 64 + j * 16 + lq;
            int reg = Cg >> 10, c = Cg & 1023;
            int h = c >> 6, hd = c & 63;
            float bb = bias[Cg];
#pragma unroll
            for (int i = 0; i < 4; ++i) {
                int Rb = mBase + wm * 64 + i * 16 + lg * 4;
#pragma unroll
                for (int r = 0; r < 4; ++r) {
                    int R = Rb + r, b = R >> 11, t = R & (T_ - 1);
                    unsigned short o = f2bf(acc[i][j][r] + bb);
                    if (reg == 0)
                        Qb[(((size_t)(b * H_ + h) * T_ + t) * HD_) + hd] = o;
                    else if (reg == 1)
                        Kb[(((size_t)(b * H_ + h) * T_ + t) * HD_) + hd] = o;
                    else
                        VTb[(((size_t)(b * H_ + h) * HD_ + hd) * T_) + t] = o;
                }
            }
        }
    }
}

// ---------------------------------------------------------------------------
// combine split-K partials + bias -> d_out (fp32)
// ---------------------------------------------------------------------------
__global__ __launch_bounds__(256) void combine_out(
    const float* __restrict__ p0, const float* __restrict__ p1,
    const float* __restrict__ bo, float* __restrict__ out)
{
    int i = blockIdx.x * 256 + threadIdx.x;   // over M*N/4
    float4 a = ((const float4*)p0)[i];
    float4 b = ((const float4*)p1)[i];
    float4 bb = ((const float4*)bo)[i & 255];
    float4 o = {a.x + b.x + bb.x, a.y + b.y + bb.y,
                a.z + b.z + bb.z, a.w + b.w + bb.w};
    ((float4*)out)[i] = o;
}

// ---------------------------------------------------------------------------
// Chunked scan pass 1
// ---------------------------------------------------------------------------
__global__ __launch_bounds__(256) void scan_partial(
    const float* __restrict__ xbaseT, const float* __restrict__ deltaT,
    const float* __restrict__ BmT, const float* __restrict__ A_log,
    float* __restrict__ Pbuf, float* __restrict__ Lbuf)
{
    const int tid = threadIdx.x;
    const int s = tid & 15;
    const int cl = tid >> 4;
    const int cg = blockIdx.x & 63;
    const int k  = (blockIdx.x >> 6) & (NCH - 1);
    const int b  = blockIdx.x >> 11;
    const int c  = cg * 16 + cl;

    const float a = -__expf(A_log[c * S_ + s]);
    const int tb = k * CHL;
    const float* dp = deltaT + ((size_t)b * C_ + c) * T_ + tb;
    const float* xp = xbaseT + ((size_t)b * C_ + c) * T_ + tb;
    const float* bp = BmT + ((size_t)b * S_ + s) * T_ + tb;

    float L = 0.f, sumd = 0.f;
    for (int t0 = 0; t0 < CHL; t0 += 4) {
        float4 d4 = *(const float4*)&dp[t0];
        float4 x4 = *(const float4*)&xp[t0];
        float4 b4 = *(const float4*)&bp[t0];
        float dv[4] = {d4.x, d4.y, d4.z, d4.w};
        float xv[4] = {x4.x, x4.y, x4.z, x4.w};
        float bv[4] = {b4.x, b4.y, b4.z, b4.w};
#pragma unroll
        for (int q = 0; q < 4; ++q) {
            float bar = __expf(dv[q] * a);
            L = fmaf(bar, L, dv[q] * xv[q] * bv[q]);
            sumd += dv[q];
        }
    }
    int idx = (blockIdx.x << 8) + tid;
    Pbuf[idx] = __expf(a * sumd);
    Lbuf[idx] = L;
}

// ---------------------------------------------------------------------------
// Chunked scan pass 2
// ---------------------------------------------------------------------------
__global__ __launch_bounds__(256) void scan_final(
    const float* __restrict__ xbaseT, const float* __restrict__ deltaT,
    const float* __restrict__ BmT, const float* __restrict__ CmT,
    const float* __restrict__ A_log, const float* __restrict__ Pbuf,
    const float* __restrict__ Lbuf, float* __restrict__ hyb)
{
    const int tid = threadIdx.x;
    const int s = tid & 15;
    const int cl = tid >> 4;
    const int cg = blockIdx.x & 63;
    const int k  = (blockIdx.x >> 6) & (NCH - 1);
    const int b  = blockIdx.x >> 11;
    const int c  = cg * 16 + cl;

    float h = 0.f;
    for (int k2 = 0; k2 < k; ++k2) {
        int idx = ((((b << 5) | k2) << 6 | cg) << 8) | tid;
        h = fmaf(Pbuf[idx], h, Lbuf[idx]);
    }

    const float a = -__expf(A_log[c * S_ + s]);
    const int tb = k * CHL;
    const float* dp = deltaT + ((size_t)b * C_ + c) * T_ + tb;
    const float* xp = xbaseT + ((size_t)b * C_ + c) * T_ + tb;
    const float* bp = BmT + ((size_t)b * S_ + s) * T_ + tb;
    const float* cp = CmT + ((size_t)b * S_ + s) * T_ + tb;
    float* hp = hyb + ((size_t)b * T_ + tb) * C_ + c;

    for (int t0 = 0; t0 < CHL; t0 += 4) {
        float4 d4 = *(const float4*)&dp[t0];
        float4 x4 = *(const float4*)&xp[t0];
        float4 b4 = *(const float4*)&bp[t0];
        float4 c4 = *(const float4*)&cp[t0];
        float dv[4] = {d4.x, d4.y, d4.z, d4.w};
        float xv[4] = {x4.x, x4.y, x4.z, x4.w};
        float bv[4] = {b4.x, b4.y, b4.z, b4.w};
        float cv[4] = {c4.x, c4.y, c4.z, c4.w};
#pragma unroll
        for (int q = 0; q < 4; ++q) {
            float bar = __expf(dv[q] * a);
            h = fmaf(bar, h, dv[q] * xv[q] * bv[q]);
            float contrib = h * cv[q];
            contrib += __shfl_xor(contrib, 1, 64);
            contrib += __shfl_xor(contrib, 2, 64);
            contrib += __shfl_xor(contrib, 4, 64);
            contrib += __shfl_xor(contrib, 8, 64);
            if (s == 0) hp[(size_t)(t0 + q) * C_] = xv[q] + contrib;
        }
    }
}

// ---------------------------------------------------------------------------
// LayerNorm over C=1024, bf16 output.
// ---------------------------------------------------------------------------
__global__ __launch_bounds__(256) void layernorm_kernel(
    const float* __restrict__ in, const float* __restrict__ g,
    const float* __restrict__ beta, unsigned short* __restrict__ out)
{
    const int row = blockIdx.x;
    const float* rp = in + (size_t)row * C_;
    const int c = threadIdx.x * 4;
    float4 v = *(const float4*)&rp[c];
    float sum = v.x + v.y + v.z + v.w;
    float sq = v.x * v.x + v.y * v.y + v.z * v.z + v.w * v.w;
#pragma unroll
    for (int off = 1; off < 64; off <<= 1) {
        sum += __shfl_xor(sum, off, 64);
        sq += __shfl_xor(sq, off, 64);
    }
    __shared__ float sS[4], sQ[4];
    int wave = threadIdx.x >> 6, lane = threadIdx.x & 63;
    if (lane == 0) { sS[wave] = sum; sQ[wave] = sq; }
    __syncthreads();
    sum = sS[0] + sS[1] + sS[2] + sS[3];
    sq = sQ[0] + sQ[1] + sQ[2] + sQ[3];
    const float mu = sum * (1.f / C_);
    const float var = sq * (1.f / C_) - mu * mu;
    const float rstd = rsqrtf(var + 1e-5f);
    float4 gg = *(const float4*)&g[c];
    float4 bb = *(const float4*)&beta[c];
    ushort4v o;
    o.x = f2bf((v.x - mu) * rstd * gg.x + bb.x);
    o.y = f2bf((v.y - mu) * rstd * gg.y + bb.y);
    o.z = f2bf((v.z - mu) * rstd * gg.z + bb.z);
    o.w = f2bf((v.w - mu) * rstd * gg.w + bb.w);
    *(ushort4v*)&out[(size_t)row * C_ + c] = o;
}

// ---------------------------------------------------------------------------
// MFMA flash attention v2: BK=128, register-prefetch pipeline, ones-column
// row-sum trick (l_i = extra PV accumulator block), Q fragments in registers.
// Blocks handle q-tile pair (31-p, p): uniform 17 K-tiles of 128 per block.
// LDS: Ks 128x72 + Vs 80x136 (rows 64..79 = 1.0) + Ps 64x136 = 57.6 KB.
// ---------------------------------------------------------------------------
#define BKT 128
#define KP  72
#define VP  136
__global__ __launch_bounds__(256) void attn_mfma(
    const unsigned short* __restrict__ Q, const unsigned short* __restrict__ K,
    const unsigned short* __restrict__ VT, const float* __restrict__ temp,
    unsigned short* __restrict__ out)
{
    __shared__ __align__(16) unsigned short Ks[BKT * KP];
    __shared__ __align__(16) unsigned short Vs[80 * VP];
    __shared__ __align__(16) unsigned short Ps[64 * VP];

    const int tid = threadIdx.x;
    const int w = tid >> 6, lane = tid & 63;
    const int lq = lane & 15, lg = lane >> 4;
    const int p  = blockIdx.x & 15;
    const int bh = blockIdx.x >> 4;
    const int b = bh >> 4, h = bh & 15;

    const float scale = softplus_f(temp[h]) * 0.125f;
    const unsigned short* Qp = Q + (size_t)bh * T_ * HD_;
    const unsigned short* Kp = K + (size_t)bh * T_ * HD_;
    const unsigned short* Vp = VT + (size_t)bh * HD_ * T_;

    // stage ones rows (dims 64..79, keys 0..127) once
    {
        int r = 64 + (tid >> 4), o = (tid & 15) * 8;
        ushort8 ones = {0x3f80, 0x3f80, 0x3f80, 0x3f80,
                        0x3f80, 0x3f80, 0x3f80, 0x3f80};
        *(ushort8*)&Vs[r * VP + o] = ones;
    }

    ushort8 kreg[4], vreg[4];
    #define LOADKV(jtv)                                                        \
        do {                                                                   \
            int kb = (jtv) * BKT;                                              \
            _Pragma("unroll")                                                  \
            for (int q2 = 0; q2 < 4; ++q2) {                                   \
                int c = tid + q2 * 256;                                        \
                kreg[q2] = *(const ushort8*)&Kp[(size_t)(kb + (c >> 3)) * HD_  \
                                                + (c & 7) * 8];                \
                vreg[q2] = *(const ushort8*)&Vp[(size_t)(c >> 4) * T_ + kb     \
                                                + (c & 15) * 8];               \
            }                                                                  \
        } while (0)

    for (int half = 0; half < 2; ++half) {
        const int qi = half ? p : (31 - p);
        const int qbase = qi * 64;
        const int nT = (qbase + 64 + BKT - 1) / BKT;

        // Q fragments straight to registers (row = qbase + w*16 + lq)
        short8 qf[2];
#pragma unroll
        for (int s = 0; s < 2; ++s)
            qf[s] = *(const short8*)&Qp[(size_t)(qbase + w * 16 + lq) * HD_
                                        + s * 32 + lg * 8];
        LOADKV(0);

        float m_i[4];
        f32x4 o[5];
#pragma unroll
        for (int r = 0; r < 4; ++r) m_i[r] = -INFINITY;
#pragma unroll
        for (int j = 0; j < 5; ++j) o[j] = (f32x4){0.f, 0.f, 0.f, 0.f};

        for (int jt = 0; jt < nT; ++jt) {
            const int kbase = jt * BKT;
            const bool last = (jt == nT - 1);
            __syncthreads();
#pragma unroll
            for (int q2 = 0; q2 < 4; ++q2) {
                int c = tid + q2 * 256;
                *(ushort8*)&Ks[(c >> 3) * KP + (c & 7) * 8] = kreg[q2];
                *(ushort8*)&Vs[(c >> 4) * VP + (c & 15) * 8] = vreg[q2];
            }
            __syncthreads();
            if (jt + 1 < nT) LOADKV(jt + 1);

            // S = Q K^T : 16 q-rows x 128 keys per wave
            f32x4 sacc[8];
#pragma unroll
            for (int j = 0; j < 8; ++j) sacc[j] = (f32x4){0.f, 0.f, 0.f, 0.f};
#pragma unroll
            for (int s = 0; s < 2; ++s) {
#pragma unroll
                for (int j = 0; j < 8; ++j) {
                    short8 kf = *(const short8*)&Ks[(j * 16 + lq) * KP
                                                    + s * 32 + lg * 8];
                    sacc[j] = __builtin_amdgcn_mfma_f32_16x16x32_bf16(
                        qf[s], kf, sacc[j], 0, 0, 0);
                }
            }

            // online softmax (max chain only; sums via ones-column)
#pragma unroll
            for (int r = 0; r < 4; ++r) {
                int qrow = qbase + w * 16 + lg * 4 + r;
                float sv[8];
#pragma unroll
                for (int j = 0; j < 8; ++j) {
                    sv[j] = sacc[j][r] * scale;
                    if (last && (kbase + j * 16 + lq > qrow)) sv[j] = -INFINITY;
                }
                float mx = sv[0];
#pragma unroll
                for (int j = 1; j < 8; ++j) mx = fmaxf(mx, sv[j]);
                mx = fmaxf(mx, __shfl_xor(mx, 1, 64));
                mx = fmaxf(mx, __shfl_xor(mx, 2, 64));
                mx = fmaxf(mx, __shfl_xor(mx, 4, 64));
                mx = fmaxf(mx, __shfl_xor(mx, 8, 64));
                float mnew = fmaxf(m_i[r], mx);
                float alpha = __expf(m_i[r] - mnew);
                m_i[r] = mnew;
#pragma unroll
                for (int j = 0; j < 5; ++j) o[j][r] *= alpha;
#pragma unroll
                for (int j = 0; j < 8; ++j)
                    Ps[(w * 16 + lg * 4 + r) * VP + j * 16 + lq] =
                        f2bf(__expf(sv[j] - mnew));
            }

            // O += P @ [V; ones] : j=4 block accumulates row sums (l_i)
#pragma unroll
            for (int s2 = 0; s2 < 4; ++s2) {
                short8 pf = *(const short8*)&Ps[(w * 16 + lq) * VP
                                                + s2 * 32 + lg * 8];
#pragma unroll
                for (int j = 0; j < 5; ++j) {
                    short8 vf = *(const short8*)&Vs[(j * 16 + lq) * VP
                                                    + s2 * 32 + lg * 8];
                    o[j] = __builtin_amdgcn_mfma_f32_16x16x32_bf16(
                        pf, vf, o[j], 0, 0, 0);
                }
            }
        }

        // epilogue: l = o[4][r] (every lane holds the row sum)
#pragma unroll
        for (int r = 0; r < 4; ++r) {
            float inv = 1.f / o[4][r];
            int qrow = qbase + w * 16 + lg * 4 + r;
#pragma unroll
            for (int j = 0; j < 4; ++j)
                out[((size_t)(b * T_ + qrow)) * C_ + h * 64 + j * 16 + lq] =
                    f2bf(o[j][r] * inv);
        }
    }
    #undef LOADKV
}

// ---------------------------------------------------------------------------
extern "C" void kernel_launch(void* const* d_in, const int* in_sizes, int n_in,
                              void* d_out, int out_size, void* d_ws, size_t ws_size,
                              hipStream_t stream)
{
    const float* x     = (const float*)d_in[0];
    const float* A_log = (const float*)d_in[1];
    const float* Wd    = (const float*)d_in[2];
    const float* bd    = (const float*)d_in[3];
    const float* WB    = (const float*)d_in[4];
    const float* WC    = (const float*)d_in[5];
    const float* Wq    = (const float*)d_in[6];
    const float* bq    = (const float*)d_in[7];
    const float* Wk    = (const float*)d_in[8];
    const float* bk    = (const float*)d_in[9];
    const float* Wv    = (const float*)d_in[10];
    const float* bv    = (const float*)d_in[11];
    const float* Wx    = (const float*)d_in[12];
    const float* bx    = (const float*)d_in[13];
    const float* Wo    = (const float*)d_in[14];
    const float* bo    = (const float*)d_in[15];
    const float* ln_g  = (const float*)d_in[16];
    const float* ln_b  = (const float*)d_in[17];
    const float* temp  = (const float*)d_in[18];

    char* wsb = (char*)d_ws;
    const size_t MB = 1024 * 1024;
    const size_t HMB = 512 * 1024;
    // Timeline-disjoint workspace map (identical to round 5 — verified):
    //  [0,8):      xb -> Pbuf/Lbuf -> hybrid -> P1 [0,16)
    //  [8,12.5):   Astack + biasPD/biasQKV
    //  [12.5,18.5): WqkvT
    //  [18.5,20.5): deltaT head -> WoT (post-attention)
    //  [18.5,34.5): deltaT
    //  [20.5,28.5): Qb -> P0 [20.5,36.5)
    //  [28.5,36.5): Kb
    //  [34.5,50.5): xbaseT
    //  [36.5,44.5): VTb (over dead xbaseT)
    //  [44.5,52.5): attnO (over dead xbaseT tail / dead hyb head)
    //  [50.5,66.5): hyb
    //  [66.5,67):  BmT/CmT
    unsigned short* xb      = (unsigned short*)(wsb);
    float* Pbuf             = (float*)(wsb);
    float* Lbuf             = (float*)(wsb + 4 * MB);
    unsigned short* hybrid  = (unsigned short*)(wsb);
    float* P1               = (float*)(wsb);
    unsigned short* Astack  = (unsigned short*)(wsb + 8 * MB);
    float* biasPD           = (float*)(wsb + 8 * MB + (size_t)2176 * 2048);
    float* biasQKV          = biasPD + 2176;
    unsigned short* WqkvT   = (unsigned short*)(wsb + 12 * MB + HMB);
    unsigned short* WoT     = (unsigned short*)(wsb + 18 * MB + HMB);
    float* deltaT           = (float*)(wsb + 18 * MB + HMB);
    float* xbaseT           = (float*)(wsb + 34 * MB + HMB);
    float* hyb              = (float*)(wsb + 50 * MB + HMB);
    float* BmT              = (float*)(wsb + 66 * MB + HMB);
    float* CmT              = BmT + (size_t)B_ * S_ * T_;
    unsigned short* Qb      = (unsigned short*)(wsb + 20 * MB + HMB);
    unsigned short* Kb      = (unsigned short*)(wsb + 28 * MB + HMB);
    unsigned short* VTb     = (unsigned short*)(wsb + 36 * MB + HMB);
    unsigned short* attnO   = (unsigned short*)(wsb + 44 * MB + HMB);
    float* P0               = (float*)(wsb + 20 * MB + HMB);

    // ---- prep ----
    cast_bf16<<<4096, 256, 0, stream>>>(x, xb, (B_ * T_ * C_) / 4);
    wtrans_multi<<<dim3(32, 32, 5), 256, 0, stream>>>(Wx, Wd, Wq, Wk, Wv,
                                                      Astack, WqkvT);
    prep_misc<<<149, 256, 0, stream>>>(WB, WC, bx, bd, bq, bk, bv,
                                       Astack, biasPD, biasQKV);

    // ---- fused projection-T GEMM ----
    gemm_mfma<<<dim3(32, 17, 1), 256, 0, stream>>>(
        Astack, xb, biasPD, xbaseT, deltaT, BmT, CmT,
        2176, 4096, 1024, 1024, 1);

    // ---- chunk-parallel scan ----
    const int scanBlocks = B_ * NCH * (C_ / 16);   // 4096
    scan_partial<<<scanBlocks, 256, 0, stream>>>(xbaseT, deltaT, BmT, A_log,
                                                 Pbuf, Lbuf);
    scan_final<<<scanBlocks, 256, 0, stream>>>(xbaseT, deltaT, BmT, CmT, A_log,
                                               Pbuf, Lbuf, hyb);

    // ---- layernorm ----
    layernorm_kernel<<<B_ * T_, 256, 0, stream>>>(hyb, ln_g, ln_b, hybrid);

    // ---- fused QKV GEMM ----
    gemm_mfma<<<dim3(24, 32, 1), 256, 0, stream>>>(
        hybrid, WqkvT, biasQKV, Qb, Kb, VTb, nullptr,
        4096, 3072, 1024, 1024, 2);

    // ---- attention ----
    attn_mfma<<<B_ * H_ * 16, 256, 0, stream>>>(Qb, Kb, VTb, temp, attnO);

    // ---- Wo transpose + split-K GEMM + combine ----
    wtrans<<<dim3(32, 32), 256, 0, stream>>>(Wo, WoT);
    gemm_mfma<<<dim3(8, 32, 2), 256, 0, stream>>>(
        attnO, WoT, nullptr, P0, P1, nullptr, nullptr,
        4096, 1024, 512, 1024, 0);
    combine_out<<<4096, 256, 0, stream>>>(P0, P1, bo, (float*)d_out);
}

// Round 7
// 505.022 us; speedup vs baseline: 1.2301x; 1.2301x over previous
//
#include <hip/hip_runtime.h>
#include <math.h>

#define B_  2
#define T_  2048
#define C_  1024
#define H_  16
#define S_  16
#define HD_ 64
#define NCH 32
#define CHL 64   /* T_/NCH */

typedef short  short8  __attribute__((ext_vector_type(8)));
typedef unsigned short ushort8 __attribute__((ext_vector_type(8)));
typedef unsigned short ushort4v __attribute__((ext_vector_type(4)));
typedef float  f32x4   __attribute__((ext_vector_type(4)));

__device__ __forceinline__ float softplus_f(float v) {
    return fmaxf(v, 0.f) + log1pf(__expf(-fabsf(v)));
}

__device__ __forceinline__ unsigned short f2bf(float x) {
    unsigned u = __float_as_uint(x);
    u += 0x7fffu + ((u >> 16) & 1u);
    return (unsigned short)(u >> 16);
}

// ---------------------------------------------------------------------------
// cast fp32 -> bf16 (vectorized), n4 = n/4
// ---------------------------------------------------------------------------
__global__ __launch_bounds__(256) void cast_bf16(const float* __restrict__ in,
                                                 unsigned short* __restrict__ out,
                                                 int n4)
{
    int i = blockIdx.x * 256 + threadIdx.x;
    if (i >= n4) return;
    float4 v = ((const float4*)in)[i];
    ushort4v o = {f2bf(v.x), f2bf(v.y), f2bf(v.z), f2bf(v.w)};
    ((ushort4v*)out)[i] = o;
}

// ---------------------------------------------------------------------------
// transpose-cast: W (1024 x 1024 fp32) -> WT (1024 x 1024 bf16, transposed)
// ---------------------------------------------------------------------------
__device__ __forceinline__ void wtrans_body(const float* __restrict__ W,
                                            unsigned short* __restrict__ WT,
                                            int bx, int by, int tid)
{
    __shared__ float t[32][33];
    const int n0 = bx * 32, k0 = by * 32;
    const int tx = tid & 31, ty = tid >> 5;
#pragma unroll
    for (int p = 0; p < 4; ++p)
        t[ty + p * 8][tx] = W[(size_t)(k0 + ty + p * 8) * C_ + n0 + tx];
    __syncthreads();
#pragma unroll
    for (int p = 0; p < 4; ++p)
        WT[(size_t)(n0 + ty + p * 8) * C_ + k0 + tx] = f2bf(t[tx][ty + p * 8]);
}

__global__ __launch_bounds__(256) void wtrans(const float* __restrict__ W,
                                              unsigned short* __restrict__ WT)
{
    wtrans_body(W, WT, blockIdx.x, blockIdx.y, threadIdx.x);
}

// z: 0 Wx->Astack, 1 Wd->Astack+1024 rows, 2 Wq->Wqkv, 3 Wk->+1024, 4 Wv->+2048
__global__ __launch_bounds__(256) void wtrans_multi(
    const float* __restrict__ Wx, const float* __restrict__ Wd,
    const float* __restrict__ Wq, const float* __restrict__ Wk,
    const float* __restrict__ Wv,
    unsigned short* __restrict__ Astack, unsigned short* __restrict__ Wqkv)
{
    const float* src;
    unsigned short* dst;
    switch (blockIdx.z) {
        case 0: src = Wx; dst = Astack; break;
        case 1: src = Wd; dst = Astack + (size_t)1024 * 1024; break;
        case 2: src = Wq; dst = Wqkv; break;
        case 3: src = Wk; dst = Wqkv + (size_t)1024 * 1024; break;
        default: src = Wv; dst = Wqkv + (size_t)2048 * 1024; break;
    }
    wtrans_body(src, dst, blockIdx.x, blockIdx.y, threadIdx.x);
}

// ---------------------------------------------------------------------------
// misc prep: WB/WC transposed into Astack rows 2048..2079 + stacked biases
// ---------------------------------------------------------------------------
__global__ __launch_bounds__(256) void prep_misc(
    const float* __restrict__ WB, const float* __restrict__ WC,
    const float* __restrict__ bx, const float* __restrict__ bd,
    const float* __restrict__ bq, const float* __restrict__ bk,
    const float* __restrict__ bv,
    unsigned short* __restrict__ Astack, float* __restrict__ biasPD,
    float* __restrict__ biasQKV)
{
    int gid = blockIdx.x * 256 + threadIdx.x;
    if (gid < 32768) {
        int w = gid >> 14, rem = gid & 16383;
        int s = rem >> 10, k = rem & 1023;
        const float* src = w ? WC : WB;
        Astack[(size_t)(2048 + w * 16 + s) * 1024 + k] = f2bf(src[k * 16 + s]);
    } else {
        int id = gid - 32768;
        if (id < 2176) {
            biasPD[id] = id < 1024 ? bx[id] : (id < 2048 ? bd[id - 1024] : 0.f);
        } else {
            int id2 = id - 2176;
            if (id2 < 3072)
                biasQKV[id2] = id2 < 1024 ? bq[id2]
                             : (id2 < 2048 ? bk[id2 - 1024] : bv[id2 - 2048]);
        }
    }
}

// ---------------------------------------------------------------------------
// bf16 MFMA GEMM: acc = A(M x K) @ B(N x K)^T, both lda-strided K-major bf16.
// 128x128 tile, BK=32, 256 threads = 4 waves (2x2 of 64x64).
// Staging: REGISTER-PREFETCH pipeline — next K-tile is loaded into VGPRs
// during the current tile's MFMAs, written to (single-buffer) LDS at the
// barrier. Global latency hidden behind compute; no vmcnt(0) drain at the
// barrier (the R6 profile showed MfmaUtil 4.4% from exactly that stall).
// mode 0: split-K partial fp32; z=0 -> outv, z=1 -> out2 (no bias)
// mode 1: fused projT. rows: [0,1024) xbaseT, [1024,2048) deltaT(softplus),
//         [2048,2064) BmT, [2064,2080) CmT; cols = b*T+t. bias = biasPD[row].
// mode 2: fused QKV. cols: [0,1024) Q heads (outv), [1024,2048) K heads (out2),
//         [2048,3072) V transposed (out3). bias = biasQKV[col].
// ---------------------------------------------------------------------------
__global__ __launch_bounds__(256) void gemm_mfma(
    const unsigned short* __restrict__ A, const unsigned short* __restrict__ Bm,
    const float* __restrict__ bias,
    void* __restrict__ outv, void* __restrict__ out2,
    void* __restrict__ out3, void* __restrict__ out4,
    int M, int N, int K, int lda, int mode)
{
    __shared__ __align__(16) unsigned short As[4096];   // 512 chunks x 8 bf16
    __shared__ __align__(16) unsigned short Bs[4096];

    const int tid = threadIdx.x;
    const int w = tid >> 6, lane = tid & 63;
    const int lq = lane & 15, lg = lane >> 4;
    const int wm = w >> 1, wn = w & 1;
    const int mBase = blockIdx.y * 128, nBase = blockIdx.x * 128;

    A  += (size_t)blockIdx.z * K;     // split-K column offset (z=0 for others)
    Bm += (size_t)blockIdx.z * K;

    // chunk c: ti = c>>6 (16-row tile), g = (c>>4)&3 (k-group), mrow = c&15
    const int c0 = tid, c1 = tid + 256;
    const int rA0 = ((c0 >> 6) << 4) + (c0 & 15), kO0 = ((c0 >> 4) & 3) << 3;
    const int rA1 = ((c1 >> 6) << 4) + (c1 & 15), kO1 = ((c1 >> 4) & 3) << 3;

    f32x4 acc[4][4];
#pragma unroll
    for (int i = 0; i < 4; ++i)
#pragma unroll
        for (int j = 0; j < 4; ++j) acc[i][j] = (f32x4){0.f, 0.f, 0.f, 0.f};

    const unsigned short* ga0 = A  + (size_t)(mBase + rA0) * lda + kO0;
    const unsigned short* ga1 = A  + (size_t)(mBase + rA1) * lda + kO1;
    const unsigned short* gb0 = Bm + (size_t)(nBase + rA0) * lda + kO0;
    const unsigned short* gb1 = Bm + (size_t)(nBase + rA1) * lda + kO1;

    ushort8 pa0, pa1, pb0, pb1;
    #define PREF(k0v)                                      \
        do {                                               \
            pa0 = *(const ushort8*)(ga0 + (k0v));          \
            pa1 = *(const ushort8*)(ga1 + (k0v));          \
            pb0 = *(const ushort8*)(gb0 + (k0v));          \
            pb1 = *(const ushort8*)(gb1 + (k0v));          \
        } while (0)

    PREF(0);
    for (int k0 = 0; k0 < K; k0 += 32) {
        __syncthreads();                       // prev iter's LDS reads done
        *(ushort8*)&As[c0 * 8] = pa0;
        *(ushort8*)&As[c1 * 8] = pa1;
        *(ushort8*)&Bs[c0 * 8] = pb0;
        *(ushort8*)&Bs[c1 * 8] = pb1;
        __syncthreads();
        if (k0 + 32 < K) PREF(k0 + 32);        // ride under this iter's MFMAs
        short8 a[4], b[4];
#pragma unroll
        for (int i = 0; i < 4; ++i)
            a[i] = *(const short8*)&As[((wm * 4 + i) * 64 + lg * 16 + lq) * 8];
#pragma unroll
        for (int j = 0; j < 4; ++j)
            b[j] = *(const short8*)&Bs[((wn * 4 + j) * 64 + lg * 16 + lq) * 8];
#pragma unroll
        for (int i = 0; i < 4; ++i)
#pragma unroll
            for (int j = 0; j < 4; ++j)
                acc[i][j] = __builtin_amdgcn_mfma_f32_16x16x32_bf16(
                    a[i], b[j], acc[i][j], 0, 0, 0);
    }
    #undef PREF

    if (mode == 0) {
        float* O = blockIdx.z ? (float*)out2 : (float*)outv;
#pragma unroll
        for (int i = 0; i < 4; ++i) {
            int Rb = mBase + wm * 64 + i * 16 + lg * 4;
#pragma unroll
            for (int j = 0; j < 4; ++j) {
                int Cg = nBase + wn * 64 + j * 16 + lq;
#pragma unroll
                for (int r = 0; r < 4; ++r)
                    O[(size_t)(Rb + r) * N + Cg] = acc[i][j][r];
            }
        }
    } else if (mode == 1) {
        float* xbaseT = (float*)outv;
        float* deltaT = (float*)out2;
        float* BmT    = (float*)out3;
        float* CmT    = (float*)out4;
#pragma unroll
        for (int i = 0; i < 4; ++i) {
            int Rb = mBase + wm * 64 + i * 16 + lg * 4;
            if (Rb >= 2080) continue;
            float bb[4];
#pragma unroll
            for (int r = 0; r < 4; ++r) bb[r] = bias[Rb + r];
#pragma unroll
            for (int j = 0; j < 4; ++j) {
                int Cg = nBase + wn * 64 + j * 16 + lq;
                int b = Cg >> 11, t = Cg & (T_ - 1);
#pragma unroll
                for (int r = 0; r < 4; ++r) {
                    int R = Rb + r;
                    float v = acc[i][j][r] + bb[r];
                    if (Rb < 1024) {
                        xbaseT[((size_t)b * C_ + R) * T_ + t] = v;
                    } else if (Rb < 2048) {
                        deltaT[((size_t)b * C_ + (R - 1024)) * T_ + t] =
                            softplus_f(v);
                    } else if (Rb < 2064) {
                        BmT[((size_t)b * S_ + (R - 2048)) * T_ + t] = v;
                    } else {
                        CmT[((size_t)b * S_ + (R - 2064)) * T_ + t] = v;
                    }
                }
            }
        }
    } else { // mode 2: QKV
        unsigned short* Qb  = (unsigned short*)outv;
        unsigned short* Kb  = (unsigned short*)out2;
        unsigned short* VTb = (unsigned short*)out3;
#pragma unroll
        for (int j = 0; j < 4; ++j) {
            int Cg = nBase + wn * 64 + j * 16 + lq;
            int reg = Cg >> 10, c = Cg & 1023;
            int h = c >> 6, hd = c & 63;
            float bb = bias[Cg];
#pragma unroll
            for (int i = 0; i < 4; ++i) {
                int Rb = mBase + wm * 64 + i * 16 + lg * 4;
#pragma unroll
                for (int r = 0; r < 4; ++r) {
                    int R = Rb + r, b = R >> 11, t = R & (T_ - 1);
                    unsigned short o = f2bf(acc[i][j][r] + bb);
                    if (reg == 0)
                        Qb[(((size_t)(b * H_ + h) * T_ + t) * HD_) + hd] = o;
                    else if (reg == 1)
                        Kb[(((size_t)(b * H_ + h) * T_ + t) * HD_) + hd] = o;
                    else
                        VTb[(((size_t)(b * H_ + h) * HD_ + hd) * T_) + t] = o;
                }
            }
        }
    }
}

// ---------------------------------------------------------------------------
// combine split-K partials + bias -> d_out (fp32)
// ---------------------------------------------------------------------------
__global__ __launch_bounds__(256) void combine_out(
    const float* __restrict__ p0, const float* __restrict__ p1,
    const float* __restrict__ bo, float* __restrict__ out)
{
    int i = blockIdx.x * 256 + threadIdx.x;   // over M*N/4
    float4 a = ((const float4*)p0)[i];
    float4 b = ((const float4*)p1)[i];
    float4 bb = ((const float4*)bo)[i & 255];
    float4 o = {a.x + b.x + bb.x, a.y + b.y + bb.y,
                a.z + b.z + bb.z, a.w + b.w + bb.w};
    ((float4*)out)[i] = o;
}

// ---------------------------------------------------------------------------
// Chunked scan pass 1
// ---------------------------------------------------------------------------
__global__ __launch_bounds__(256) void scan_partial(
    const float* __restrict__ xbaseT, const float* __restrict__ deltaT,
    const float* __restrict__ BmT, const float* __restrict__ A_log,
    float* __restrict__ Pbuf, float* __restrict__ Lbuf)
{
    const int tid = threadIdx.x;
    const int s = tid & 15;
    const int cl = tid >> 4;
    const int cg = blockIdx.x & 63;
    const int k  = (blockIdx.x >> 6) & (NCH - 1);
    const int b  = blockIdx.x >> 11;
    const int c  = cg * 16 + cl;

    const float a = -__expf(A_log[c * S_ + s]);
    const int tb = k * CHL;
    const float* dp = deltaT + ((size_t)b * C_ + c) * T_ + tb;
    const float* xp = xbaseT + ((size_t)b * C_ + c) * T_ + tb;
    const float* bp = BmT + ((size_t)b * S_ + s) * T_ + tb;

    float L = 0.f, sumd = 0.f;
    for (int t0 = 0; t0 < CHL; t0 += 4) {
        float4 d4 = *(const float4*)&dp[t0];
        float4 x4 = *(const float4*)&xp[t0];
        float4 b4 = *(const float4*)&bp[t0];
        float dv[4] = {d4.x, d4.y, d4.z, d4.w};
        float xv[4] = {x4.x, x4.y, x4.z, x4.w};
        float bv[4] = {b4.x, b4.y, b4.z, b4.w};
#pragma unroll
        for (int q = 0; q < 4; ++q) {
            float bar = __expf(dv[q] * a);
            L = fmaf(bar, L, dv[q] * xv[q] * bv[q]);
            sumd += dv[q];
        }
    }
    int idx = (blockIdx.x << 8) + tid;
    Pbuf[idx] = __expf(a * sumd);
    Lbuf[idx] = L;
}

// ---------------------------------------------------------------------------
// Chunked scan pass 2
// ---------------------------------------------------------------------------
__global__ __launch_bounds__(256) void scan_final(
    const float* __restrict__ xbaseT, const float* __restrict__ deltaT,
    const float* __restrict__ BmT, const float* __restrict__ CmT,
    const float* __restrict__ A_log, const float* __restrict__ Pbuf,
    const float* __restrict__ Lbuf, float* __restrict__ hyb)
{
    const int tid = threadIdx.x;
    const int s = tid & 15;
    const int cl = tid >> 4;
    const int cg = blockIdx.x & 63;
    const int k  = (blockIdx.x >> 6) & (NCH - 1);
    const int b  = blockIdx.x >> 11;
    const int c  = cg * 16 + cl;

    float h = 0.f;
    for (int k2 = 0; k2 < k; ++k2) {
        int idx = ((((b << 5) | k2) << 6 | cg) << 8) | tid;
        h = fmaf(Pbuf[idx], h, Lbuf[idx]);
    }

    const float a = -__expf(A_log[c * S_ + s]);
    const int tb = k * CHL;
    const float* dp = deltaT + ((size_t)b * C_ + c) * T_ + tb;
    const float* xp = xbaseT + ((size_t)b * C_ + c) * T_ + tb;
    const float* bp = BmT + ((size_t)b * S_ + s) * T_ + tb;
    const float* cp = CmT + ((size_t)b * S_ + s) * T_ + tb;
    float* hp = hyb + ((size_t)b * T_ + tb) * C_ + c;

    for (int t0 = 0; t0 < CHL; t0 += 4) {
        float4 d4 = *(const float4*)&dp[t0];
        float4 x4 = *(const float4*)&xp[t0];
        float4 b4 = *(const float4*)&bp[t0];
        float4 c4 = *(const float4*)&cp[t0];
        float dv[4] = {d4.x, d4.y, d4.z, d4.w};
        float xv[4] = {x4.x, x4.y, x4.z, x4.w};
        float bv[4] = {b4.x, b4.y, b4.z, b4.w};
        float cv[4] = {c4.x, c4.y, c4.z, c4.w};
#pragma unroll
        for (int q = 0; q < 4; ++q) {
            float bar = __expf(dv[q] * a);
            h = fmaf(bar, h, dv[q] * xv[q] * bv[q]);
            float contrib = h * cv[q];
            contrib += __shfl_xor(contrib, 1, 64);
            contrib += __shfl_xor(contrib, 2, 64);
            contrib += __shfl_xor(contrib, 4, 64);
            contrib += __shfl_xor(contrib, 8, 64);
            if (s == 0) hp[(size_t)(t0 + q) * C_] = xv[q] + contrib;
        }
    }
}

// ---------------------------------------------------------------------------
// LayerNorm over C=1024, bf16 output.
// ---------------------------------------------------------------------------
__global__ __launch_bounds__(256) void layernorm_kernel(
    const float* __restrict__ in, const float* __restrict__ g,
    const float* __restrict__ beta, unsigned short* __restrict__ out)
{
    const int row = blockIdx.x;
    const float* rp = in + (size_t)row * C_;
    const int c = threadIdx.x * 4;
    float4 v = *(const float4*)&rp[c];
    float sum = v.x + v.y + v.z + v.w;
    float sq = v.x * v.x + v.y * v.y + v.z * v.z + v.w * v.w;
#pragma unroll
    for (int off = 1; off < 64; off <<= 1) {
        sum += __shfl_xor(sum, off, 64);
        sq += __shfl_xor(sq, off, 64);
    }
    __shared__ float sS[4], sQ[4];
    int wave = threadIdx.x >> 6, lane = threadIdx.x & 63;
    if (lane == 0) { sS[wave] = sum; sQ[wave] = sq; }
    __syncthreads();
    sum = sS[0] + sS[1] + sS[2] + sS[3];
    sq = sQ[0] + sQ[1] + sQ[2] + sQ[3];
    const float mu = sum * (1.f / C_);
    const float var = sq * (1.f / C_) - mu * mu;
    const float rstd = rsqrtf(var + 1e-5f);
    float4 gg = *(const float4*)&g[c];
    float4 bb = *(const float4*)&beta[c];
    ushort4v o;
    o.x = f2bf((v.x - mu) * rstd * gg.x + bb.x);
    o.y = f2bf((v.y - mu) * rstd * gg.y + bb.y);
    o.z = f2bf((v.z - mu) * rstd * gg.z + bb.z);
    o.w = f2bf((v.w - mu) * rstd * gg.w + bb.w);
    *(ushort4v*)&out[(size_t)row * C_ + c] = o;
}

// ---------------------------------------------------------------------------
// MFMA flash attention v2: BK=128, register-prefetch pipeline, ones-column
// row-sum trick (l_i = extra PV accumulator block), Q fragments in registers.
// Blocks handle q-tile pair (31-p, p): uniform 17 K-tiles of 128 per block.
// ---------------------------------------------------------------------------
#define BKT 128
#define KP  72
#define VP  136
__global__ __launch_bounds__(256) void attn_mfma(
    const unsigned short* __restrict__ Q, const unsigned short* __restrict__ K,
    const unsigned short* __restrict__ VT, const float* __restrict__ temp,
    unsigned short* __restrict__ out)
{
    __shared__ __align__(16) unsigned short Ks[BKT * KP];
    __shared__ __align__(16) unsigned short Vs[80 * VP];
    __shared__ __align__(16) unsigned short Ps[64 * VP];

    const int tid = threadIdx.x;
    const int w = tid >> 6, lane = tid & 63;
    const int lq = lane & 15, lg = lane >> 4;
    const int p  = blockIdx.x & 15;
    const int bh = blockIdx.x >> 4;
    const int b = bh >> 4, h = bh & 15;

    const float scale = softplus_f(temp[h]) * 0.125f;
    const unsigned short* Qp = Q + (size_t)bh * T_ * HD_;
    const unsigned short* Kp = K + (size_t)bh * T_ * HD_;
    const unsigned short* Vp = VT + (size_t)bh * HD_ * T_;

    // stage ones rows (dims 64..79, keys 0..127) once
    {
        int r = 64 + (tid >> 4), o = (tid & 15) * 8;
        ushort8 ones = {0x3f80, 0x3f80, 0x3f80, 0x3f80,
                        0x3f80, 0x3f80, 0x3f80, 0x3f80};
        *(ushort8*)&Vs[r * VP + o] = ones;
    }

    ushort8 kreg[4], vreg[4];
    #define LOADKV(jtv)                                                        \
        do {                                                                   \
            int kb = (jtv) * BKT;                                              \
            _Pragma("unroll")                                                  \
            for (int q2 = 0; q2 < 4; ++q2) {                                   \
                int c = tid + q2 * 256;                                        \
                kreg[q2] = *(const ushort8*)&Kp[(size_t)(kb + (c >> 3)) * HD_  \
                                                + (c & 7) * 8];                \
                vreg[q2] = *(const ushort8*)&Vp[(size_t)(c >> 4) * T_ + kb     \
                                                + (c & 15) * 8];               \
            }                                                                  \
        } while (0)

    for (int half = 0; half < 2; ++half) {
        const int qi = half ? p : (31 - p);
        const int qbase = qi * 64;
        const int nT = (qbase + 64 + BKT - 1) / BKT;

        // Q fragments straight to registers (row = qbase + w*16 + lq)
        short8 qf[2];
#pragma unroll
        for (int s = 0; s < 2; ++s)
            qf[s] = *(const short8*)&Qp[(size_t)(qbase + w * 16 + lq) * HD_
                                        + s * 32 + lg * 8];
        LOADKV(0);

        float m_i[4];
        f32x4 o[5];
#pragma unroll
        for (int r = 0; r < 4; ++r) m_i[r] = -INFINITY;
#pragma unroll
        for (int j = 0; j < 5; ++j) o[j] = (f32x4){0.f, 0.f, 0.f, 0.f};

        for (int jt = 0; jt < nT; ++jt) {
            const int kbase = jt * BKT;
            const bool last = (jt == nT - 1);
            __syncthreads();
#pragma unroll
            for (int q2 = 0; q2 < 4; ++q2) {
                int c = tid + q2 * 256;
                *(ushort8*)&Ks[(c >> 3) * KP + (c & 7) * 8] = kreg[q2];
                *(ushort8*)&Vs[(c >> 4) * VP + (c & 15) * 8] = vreg[q2];
            }
            __syncthreads();
            if (jt + 1 < nT) LOADKV(jt + 1);

            // S = Q K^T : 16 q-rows x 128 keys per wave
            f32x4 sacc[8];
#pragma unroll
            for (int j = 0; j < 8; ++j) sacc[j] = (f32x4){0.f, 0.f, 0.f, 0.f};
#pragma unroll
            for (int s = 0; s < 2; ++s) {
#pragma unroll
                for (int j = 0; j < 8; ++j) {
                    short8 kf = *(const short8*)&Ks[(j * 16 + lq) * KP
                                                    + s * 32 + lg * 8];
                    sacc[j] = __builtin_amdgcn_mfma_f32_16x16x32_bf16(
                        qf[s], kf, sacc[j], 0, 0, 0);
                }
            }

            // online softmax (max chain only; sums via ones-column)
#pragma unroll
            for (int r = 0; r < 4; ++r) {
                int qrow = qbase + w * 16 + lg * 4 + r;
                float sv[8];
#pragma unroll
                for (int j = 0; j < 8; ++j) {
                    sv[j] = sacc[j][r] * scale;
                    if (last && (kbase + j * 16 + lq > qrow)) sv[j] = -INFINITY;
                }
                float mx = sv[0];
#pragma unroll
                for (int j = 1; j < 8; ++j) mx = fmaxf(mx, sv[j]);
                mx = fmaxf(mx, __shfl_xor(mx, 1, 64));
                mx = fmaxf(mx, __shfl_xor(mx, 2, 64));
                mx = fmaxf(mx, __shfl_xor(mx, 4, 64));
                mx = fmaxf(mx, __shfl_xor(mx, 8, 64));
                float mnew = fmaxf(m_i[r], mx);
                float alpha = __expf(m_i[r] - mnew);
                m_i[r] = mnew;
#pragma unroll
                for (int j = 0; j < 5; ++j) o[j][r] *= alpha;
#pragma unroll
                for (int j = 0; j < 8; ++j)
                    Ps[(w * 16 + lg * 4 + r) * VP + j * 16 + lq] =
                        f2bf(__expf(sv[j] - mnew));
            }

            // O += P @ [V; ones] : j=4 block accumulates row sums (l_i)
#pragma unroll
            for (int s2 = 0; s2 < 4; ++s2) {
                short8 pf = *(const short8*)&Ps[(w * 16 + lq) * VP
                                                + s2 * 32 + lg * 8];
#pragma unroll
                for (int j = 0; j < 5; ++j) {
                    short8 vf = *(const short8*)&Vs[(j * 16 + lq) * VP
                                                    + s2 * 32 + lg * 8];
                    o[j] = __builtin_amdgcn_mfma_f32_16x16x32_bf16(
                        pf, vf, o[j], 0, 0, 0);
                }
            }
        }

        // epilogue: l = o[4][r] (every lane holds the row sum)
#pragma unroll
        for (int r = 0; r < 4; ++r) {
            float inv = 1.f / o[4][r];
            int qrow = qbase + w * 16 + lg * 4 + r;
#pragma unroll
            for (int j = 0; j < 4; ++j)
                out[((size_t)(b * T_ + qrow)) * C_ + h * 64 + j * 16 + lq] =
                    f2bf(o[j][r] * inv);
        }
    }
    #undef LOADKV
}

// ---------------------------------------------------------------------------
extern "C" void kernel_launch(void* const* d_in, const int* in_sizes, int n_in,
                              void* d_out, int out_size, void* d_ws, size_t ws_size,
                              hipStream_t stream)
{
    const float* x     = (const float*)d_in[0];
    const float* A_log = (const float*)d_in[1];
    const float* Wd    = (const float*)d_in[2];
    const float* bd    = (const float*)d_in[3];
    const float* WB    = (const float*)d_in[4];
    const float* WC    = (const float*)d_in[5];
    const float* Wq    = (const float*)d_in[6];
    const float* bq    = (const float*)d_in[7];
    const float* Wk    = (const float*)d_in[8];
    const float* bk    = (const float*)d_in[9];
    const float* Wv    = (const float*)d_in[10];
    const float* bv    = (const float*)d_in[11];
    const float* Wx    = (const float*)d_in[12];
    const float* bx    = (const float*)d_in[13];
    const float* Wo    = (const float*)d_in[14];
    const float* bo    = (const float*)d_in[15];
    const float* ln_g  = (const float*)d_in[16];
    const float* ln_b  = (const float*)d_in[17];
    const float* temp  = (const float*)d_in[18];

    char* wsb = (char*)d_ws;
    const size_t MB = 1024 * 1024;
    const size_t HMB = 512 * 1024;
    // Timeline-disjoint workspace map (identical to round 5/6 — verified):
    //  [0,8):      xb -> Pbuf/Lbuf -> hybrid -> P1 [0,16)
    //  [8,12.5):   Astack + biasPD/biasQKV
    //  [12.5,18.5): WqkvT
    //  [18.5,20.5): deltaT head -> WoT (post-attention)
    //  [18.5,34.5): deltaT
    //  [20.5,28.5): Qb -> P0 [20.5,36.5)
    //  [28.5,36.5): Kb
    //  [34.5,50.5): xbaseT
    //  [36.5,44.5): VTb (over dead xbaseT)
    //  [44.5,52.5): attnO (over dead xbaseT tail / dead hyb head)
    //  [50.5,66.5): hyb
    //  [66.5,67):  BmT/CmT
    unsigned short* xb      = (unsigned short*)(wsb);
    float* Pbuf             = (float*)(wsb);
    float* Lbuf             = (float*)(wsb + 4 * MB);
    unsigned short* hybrid  = (unsigned short*)(wsb);
    float* P1               = (float*)(wsb);
    unsigned short* Astack  = (unsigned short*)(wsb + 8 * MB);
    float* biasPD           = (float*)(wsb + 8 * MB + (size_t)2176 * 2048);
    float* biasQKV          = biasPD + 2176;
    unsigned short* WqkvT   = (unsigned short*)(wsb + 12 * MB + HMB);
    unsigned short* WoT     = (unsigned short*)(wsb + 18 * MB + HMB);
    float* deltaT           = (float*)(wsb + 18 * MB + HMB);
    float* xbaseT           = (float*)(wsb + 34 * MB + HMB);
    float* hyb              = (float*)(wsb + 50 * MB + HMB);
    float* BmT              = (float*)(wsb + 66 * MB + HMB);
    float* CmT              = BmT + (size_t)B_ * S_ * T_;
    unsigned short* Qb      = (unsigned short*)(wsb + 20 * MB + HMB);
    unsigned short* Kb      = (unsigned short*)(wsb + 28 * MB + HMB);
    unsigned short* VTb     = (unsigned short*)(wsb + 36 * MB + HMB);
    unsigned short* attnO   = (unsigned short*)(wsb + 44 * MB + HMB);
    float* P0               = (float*)(wsb + 20 * MB + HMB);

    // ---- prep ----
    cast_bf16<<<4096, 256, 0, stream>>>(x, xb, (B_ * T_ * C_) / 4);
    wtrans_multi<<<dim3(32, 32, 5), 256, 0, stream>>>(Wx, Wd, Wq, Wk, Wv,
                                                      Astack, WqkvT);
    prep_misc<<<149, 256, 0, stream>>>(WB, WC, bx, bd, bq, bk, bv,
                                       Astack, biasPD, biasQKV);

    // ---- fused projection-T GEMM ----
    gemm_mfma<<<dim3(32, 17, 1), 256, 0, stream>>>(
        Astack, xb, biasPD, xbaseT, deltaT, BmT, CmT,
        2176, 4096, 1024, 1024, 1);

    // ---- chunk-parallel scan ----
    const int scanBlocks = B_ * NCH * (C_ / 16);   // 4096
    scan_partial<<<scanBlocks, 256, 0, stream>>>(xbaseT, deltaT, BmT, A_log,
                                                 Pbuf, Lbuf);
    scan_final<<<scanBlocks, 256, 0, stream>>>(xbaseT, deltaT, BmT, CmT, A_log,
                                               Pbuf, Lbuf, hyb);

    // ---- layernorm ----
    layernorm_kernel<<<B_ * T_, 256, 0, stream>>>(hyb, ln_g, ln_b, hybrid);

    // ---- fused QKV GEMM ----
    gemm_mfma<<<dim3(24, 32, 1), 256, 0, stream>>>(
        hybrid, WqkvT, biasQKV, Qb, Kb, VTb, nullptr,
        4096, 3072, 1024, 1024, 2);

    // ---- attention ----
    attn_mfma<<<B_ * H_ * 16, 256, 0, stream>>>(Qb, Kb, VTb, temp, attnO);

    // ---- Wo transpose + split-K GEMM + combine ----
    wtrans<<<dim3(32, 32), 256, 0, stream>>>(Wo, WoT);
    gemm_mfma<<<dim3(8, 32, 2), 256, 0, stream>>>(
        attnO, WoT, nullptr, P0, P1, nullptr, nullptr,
        4096, 1024, 512, 1024, 0);
    combine_out<<<4096, 256, 0, stream>>>(P0, P1, bo, (float*)d_out);
}

// Round 8
// 474.658 us; speedup vs baseline: 1.3088x; 1.0640x over previous
//
#include <hip/hip_runtime.h>
#include <math.h>

#define B_  2
#define T_  2048
#define C_  1024
#define H_  16
#define S_  16
#define HD_ 64
#define NCH 32
#define CHL 64   /* T_/NCH */

typedef short  short8  __attribute__((ext_vector_type(8)));
typedef unsigned short ushort8 __attribute__((ext_vector_type(8)));
typedef unsigned short ushort4v __attribute__((ext_vector_type(4)));
typedef float  f32x4   __attribute__((ext_vector_type(4)));

__device__ __forceinline__ float softplus_f(float v) {
    return fmaxf(v, 0.f) + log1pf(__expf(-fabsf(v)));
}

__device__ __forceinline__ unsigned short f2bf(float x) {
    unsigned u = __float_as_uint(x);
    u += 0x7fffu + ((u >> 16) & 1u);
    return (unsigned short)(u >> 16);
}

// ---------------------------------------------------------------------------
// cast fp32 -> bf16 (vectorized), n4 = n/4
// ---------------------------------------------------------------------------
__global__ __launch_bounds__(256) void cast_bf16(const float* __restrict__ in,
                                                 unsigned short* __restrict__ out,
                                                 int n4)
{
    int i = blockIdx.x * 256 + threadIdx.x;
    if (i >= n4) return;
    float4 v = ((const float4*)in)[i];
    ushort4v o = {f2bf(v.x), f2bf(v.y), f2bf(v.z), f2bf(v.w)};
    ((ushort4v*)out)[i] = o;
}

// ---------------------------------------------------------------------------
// transpose-cast: W (1024 x 1024 fp32) -> WT (1024 x 1024 bf16, transposed)
// ---------------------------------------------------------------------------
__device__ __forceinline__ void wtrans_body(const float* __restrict__ W,
                                            unsigned short* __restrict__ WT,
                                            int bx, int by, int tid)
{
    __shared__ float t[32][33];
    const int n0 = bx * 32, k0 = by * 32;
    const int tx = tid & 31, ty = tid >> 5;
#pragma unroll
    for (int p = 0; p < 4; ++p)
        t[ty + p * 8][tx] = W[(size_t)(k0 + ty + p * 8) * C_ + n0 + tx];
    __syncthreads();
#pragma unroll
    for (int p = 0; p < 4; ++p)
        WT[(size_t)(n0 + ty + p * 8) * C_ + k0 + tx] = f2bf(t[tx][ty + p * 8]);
}

__global__ __launch_bounds__(256) void wtrans(const float* __restrict__ W,
                                              unsigned short* __restrict__ WT)
{
    wtrans_body(W, WT, blockIdx.x, blockIdx.y, threadIdx.x);
}

// z: 0 Wx->Astack, 1 Wd->Astack+1024 rows, 2 Wq->Wqkv, 3 Wk->+1024, 4 Wv->+2048
__global__ __launch_bounds__(256) void wtrans_multi(
    const float* __restrict__ Wx, const float* __restrict__ Wd,
    const float* __restrict__ Wq, const float* __restrict__ Wk,
    const float* __restrict__ Wv,
    unsigned short* __restrict__ Astack, unsigned short* __restrict__ Wqkv)
{
    const float* src;
    unsigned short* dst;
    switch (blockIdx.z) {
        case 0: src = Wx; dst = Astack; break;
        case 1: src = Wd; dst = Astack + (size_t)1024 * 1024; break;
        case 2: src = Wq; dst = Wqkv; break;
        case 3: src = Wk; dst = Wqkv + (size_t)1024 * 1024; break;
        default: src = Wv; dst = Wqkv + (size_t)2048 * 1024; break;
    }
    wtrans_body(src, dst, blockIdx.x, blockIdx.y, threadIdx.x);
}

// ---------------------------------------------------------------------------
// misc prep: WB/WC transposed into Astack rows 2048..2079 + stacked biases
// ---------------------------------------------------------------------------
__global__ __launch_bounds__(256) void prep_misc(
    const float* __restrict__ WB, const float* __restrict__ WC,
    const float* __restrict__ bx, const float* __restrict__ bd,
    const float* __restrict__ bq, const float* __restrict__ bk,
    const float* __restrict__ bv,
    unsigned short* __restrict__ Astack, float* __restrict__ biasPD,
    float* __restrict__ biasQKV)
{
    int gid = blockIdx.x * 256 + threadIdx.x;
    if (gid < 32768) {
        int w = gid >> 14, rem = gid & 16383;
        int s = rem >> 10, k = rem & 1023;
        const float* src = w ? WC : WB;
        Astack[(size_t)(2048 + w * 16 + s) * 1024 + k] = f2bf(src[k * 16 + s]);
    } else {
        int id = gid - 32768;
        if (id < 2176) {
            biasPD[id] = id < 1024 ? bx[id] : (id < 2048 ? bd[id - 1024] : 0.f);
        } else {
            int id2 = id - 2176;
            if (id2 < 3072)
                biasQKV[id2] = id2 < 1024 ? bq[id2]
                             : (id2 < 2048 ? bk[id2 - 1024] : bv[id2 - 2048]);
        }
    }
}

// ---------------------------------------------------------------------------
// bf16 MFMA GEMM: acc = A(M x K) @ B(N x K)^T, both lda-strided K-major bf16.
// 128x128 tile, BK=32, 256 threads = 4 waves (2x2 of 64x64).
// Register-prefetch pipeline (single LDS buffer) — verified R7 win.
// mode 0: split-K partial fp32; z=0 -> outv, z=1 -> out2 (no bias)
// mode 1: fused projT (outputs transposed (b,c,t) / (b,s,t))
// mode 2: fused QKV (Q/K heads, V transposed)
// ---------------------------------------------------------------------------
__global__ __launch_bounds__(256) void gemm_mfma(
    const unsigned short* __restrict__ A, const unsigned short* __restrict__ Bm,
    const float* __restrict__ bias,
    void* __restrict__ outv, void* __restrict__ out2,
    void* __restrict__ out3, void* __restrict__ out4,
    int M, int N, int K, int lda, int mode)
{
    __shared__ __align__(16) unsigned short As[4096];
    __shared__ __align__(16) unsigned short Bs[4096];

    const int tid = threadIdx.x;
    const int w = tid >> 6, lane = tid & 63;
    const int lq = lane & 15, lg = lane >> 4;
    const int wm = w >> 1, wn = w & 1;
    const int mBase = blockIdx.y * 128, nBase = blockIdx.x * 128;

    A  += (size_t)blockIdx.z * K;
    Bm += (size_t)blockIdx.z * K;

    const int c0 = tid, c1 = tid + 256;
    const int rA0 = ((c0 >> 6) << 4) + (c0 & 15), kO0 = ((c0 >> 4) & 3) << 3;
    const int rA1 = ((c1 >> 6) << 4) + (c1 & 15), kO1 = ((c1 >> 4) & 3) << 3;

    f32x4 acc[4][4];
#pragma unroll
    for (int i = 0; i < 4; ++i)
#pragma unroll
        for (int j = 0; j < 4; ++j) acc[i][j] = (f32x4){0.f, 0.f, 0.f, 0.f};

    const unsigned short* ga0 = A  + (size_t)(mBase + rA0) * lda + kO0;
    const unsigned short* ga1 = A  + (size_t)(mBase + rA1) * lda + kO1;
    const unsigned short* gb0 = Bm + (size_t)(nBase + rA0) * lda + kO0;
    const unsigned short* gb1 = Bm + (size_t)(nBase + rA1) * lda + kO1;

    ushort8 pa0, pa1, pb0, pb1;
    #define PREF(k0v)                                      \
        do {                                               \
            pa0 = *(const ushort8*)(ga0 + (k0v));          \
            pa1 = *(const ushort8*)(ga1 + (k0v));          \
            pb0 = *(const ushort8*)(gb0 + (k0v));          \
            pb1 = *(const ushort8*)(gb1 + (k0v));          \
        } while (0)

    PREF(0);
    for (int k0 = 0; k0 < K; k0 += 32) {
        __syncthreads();
        *(ushort8*)&As[c0 * 8] = pa0;
        *(ushort8*)&As[c1 * 8] = pa1;
        *(ushort8*)&Bs[c0 * 8] = pb0;
        *(ushort8*)&Bs[c1 * 8] = pb1;
        __syncthreads();
        if (k0 + 32 < K) PREF(k0 + 32);
        short8 a[4], b[4];
#pragma unroll
        for (int i = 0; i < 4; ++i)
            a[i] = *(const short8*)&As[((wm * 4 + i) * 64 + lg * 16 + lq) * 8];
#pragma unroll
        for (int j = 0; j < 4; ++j)
            b[j] = *(const short8*)&Bs[((wn * 4 + j) * 64 + lg * 16 + lq) * 8];
#pragma unroll
        for (int i = 0; i < 4; ++i)
#pragma unroll
            for (int j = 0; j < 4; ++j)
                acc[i][j] = __builtin_amdgcn_mfma_f32_16x16x32_bf16(
                    a[i], b[j], acc[i][j], 0, 0, 0);
    }
    #undef PREF

    if (mode == 0) {
        float* O = blockIdx.z ? (float*)out2 : (float*)outv;
#pragma unroll
        for (int i = 0; i < 4; ++i) {
            int Rb = mBase + wm * 64 + i * 16 + lg * 4;
#pragma unroll
            for (int j = 0; j < 4; ++j) {
                int Cg = nBase + wn * 64 + j * 16 + lq;
#pragma unroll
                for (int r = 0; r < 4; ++r)
                    O[(size_t)(Rb + r) * N + Cg] = acc[i][j][r];
            }
        }
    } else if (mode == 1) {
        float* xbaseT = (float*)outv;
        float* deltaT = (float*)out2;
        float* BmT    = (float*)out3;
        float* CmT    = (float*)out4;
#pragma unroll
        for (int i = 0; i < 4; ++i) {
            int Rb = mBase + wm * 64 + i * 16 + lg * 4;
            if (Rb >= 2080) continue;
            float bb[4];
#pragma unroll
            for (int r = 0; r < 4; ++r) bb[r] = bias[Rb + r];
#pragma unroll
            for (int j = 0; j < 4; ++j) {
                int Cg = nBase + wn * 64 + j * 16 + lq;
                int b = Cg >> 11, t = Cg & (T_ - 1);
#pragma unroll
                for (int r = 0; r < 4; ++r) {
                    int R = Rb + r;
                    float v = acc[i][j][r] + bb[r];
                    if (Rb < 1024) {
                        xbaseT[((size_t)b * C_ + R) * T_ + t] = v;
                    } else if (Rb < 2048) {
                        deltaT[((size_t)b * C_ + (R - 1024)) * T_ + t] =
                            softplus_f(v);
                    } else if (Rb < 2064) {
                        BmT[((size_t)b * S_ + (R - 2048)) * T_ + t] = v;
                    } else {
                        CmT[((size_t)b * S_ + (R - 2064)) * T_ + t] = v;
                    }
                }
            }
        }
    } else { // mode 2: QKV
        unsigned short* Qb  = (unsigned short*)outv;
        unsigned short* Kb  = (unsigned short*)out2;
        unsigned short* VTb = (unsigned short*)out3;
#pragma unroll
        for (int j = 0; j < 4; ++j) {
            int Cg = nBase + wn * 64 + j * 16 + lq;
            int reg = Cg >> 10, c = Cg & 1023;
            int h = c >> 6, hd = c & 63;
            float bb = bias[Cg];
#pragma unroll
            for (int i = 0; i < 4; ++i) {
                int Rb = mBase + wm * 64 + i * 16 + lg * 4;
#pragma unroll
                for (int r = 0; r < 4; ++r) {
                    int R = Rb + r, b = R >> 11, t = R & (T_ - 1);
                    unsigned short o = f2bf(acc[i][j][r] + bb);
                    if (reg == 0)
                        Qb[(((size_t)(b * H_ + h) * T_ + t) * HD_) + hd] = o;
                    else if (reg == 1)
                        Kb[(((size_t)(b * H_ + h) * T_ + t) * HD_) + hd] = o;
                    else
                        VTb[(((size_t)(b * H_ + h) * HD_ + hd) * T_) + t] = o;
                }
            }
        }
    }
}

// ---------------------------------------------------------------------------
// combine split-K partials + bias -> d_out (fp32)
// ---------------------------------------------------------------------------
__global__ __launch_bounds__(256) void combine_out(
    const float* __restrict__ p0, const float* __restrict__ p1,
    const float* __restrict__ bo, float* __restrict__ out)
{
    int i = blockIdx.x * 256 + threadIdx.x;
    float4 a = ((const float4*)p0)[i];
    float4 b = ((const float4*)p1)[i];
    float4 bb = ((const float4*)bo)[i & 255];
    float4 o = {a.x + b.x + bb.x, a.y + b.y + bb.y,
                a.z + b.z + bb.z, a.w + b.w + bb.w};
    ((float4*)out)[i] = o;
}

// ---------------------------------------------------------------------------
// Chunked scan, FOLD=4: thread handles one c with a group of 4 s-states in
// registers. Block = 64 c x 4 s-groups; grid = B*NCH*(C/64) = 1024 blocks.
// Cuts ds (shfl) ops 8x vs the 1-s-per-thread version (R7: ~40us of LDS-unit
// time). P/L summaries stored as float4 per thread, coalesced.
// ---------------------------------------------------------------------------
__global__ __launch_bounds__(256) void scan_partial(
    const float* __restrict__ xbaseT, const float* __restrict__ deltaT,
    const float* __restrict__ BmT, const float* __restrict__ A_log,
    float4* __restrict__ Pbuf, float4* __restrict__ Lbuf)
{
    const int tid = threadIdx.x;
    const int s4 = tid & 3;                   // s-group: s = s4*4 + j
    const int cm = tid >> 2;                  // 0..63
    const int cg = blockIdx.x & 15;
    const int k  = (blockIdx.x >> 4) & (NCH - 1);
    const int b  = blockIdx.x >> 9;
    const int c  = cg * 64 + cm;

    float a[4];
#pragma unroll
    for (int j = 0; j < 4; ++j)
        a[j] = -__expf(A_log[c * S_ + s4 * 4 + j]);

    const int tb = k * CHL;
    const float* dp = deltaT + ((size_t)b * C_ + c) * T_ + tb;
    const float* xp = xbaseT + ((size_t)b * C_ + c) * T_ + tb;
    const float* bp = BmT + ((size_t)(b * S_ + s4 * 4)) * T_ + tb;

    float L[4] = {0.f, 0.f, 0.f, 0.f};
    float sumd = 0.f;
    for (int t0 = 0; t0 < CHL; t0 += 4) {
        float4 d4 = *(const float4*)&dp[t0];
        float4 x4 = *(const float4*)&xp[t0];
        float dv[4] = {d4.x, d4.y, d4.z, d4.w};
        float xv[4] = {x4.x, x4.y, x4.z, x4.w};
        float bv[4][4];
#pragma unroll
        for (int j = 0; j < 4; ++j) {
            float4 b4 = *(const float4*)&bp[(size_t)j * T_ + t0];
            bv[j][0] = b4.x; bv[j][1] = b4.y; bv[j][2] = b4.z; bv[j][3] = b4.w;
        }
#pragma unroll
        for (int q = 0; q < 4; ++q) {
            float u = dv[q] * xv[q];
            sumd += dv[q];
#pragma unroll
            for (int j = 0; j < 4; ++j)
                L[j] = fmaf(__expf(dv[q] * a[j]), L[j], u * bv[j][q]);
        }
    }
    int gid = blockIdx.x * 256 + tid;
    float4 P4 = {__expf(a[0] * sumd), __expf(a[1] * sumd),
                 __expf(a[2] * sumd), __expf(a[3] * sumd)};
    float4 L4 = {L[0], L[1], L[2], L[3]};
    Pbuf[gid] = P4;
    Lbuf[gid] = L4;
}

__global__ __launch_bounds__(256) void scan_final(
    const float* __restrict__ xbaseT, const float* __restrict__ deltaT,
    const float* __restrict__ BmT, const float* __restrict__ CmT,
    const float* __restrict__ A_log, const float4* __restrict__ Pbuf,
    const float4* __restrict__ Lbuf, float* __restrict__ hyb)
{
    const int tid = threadIdx.x;
    const int s4 = tid & 3;
    const int cm = tid >> 2;
    const int cg = blockIdx.x & 15;
    const int k  = (blockIdx.x >> 4) & (NCH - 1);
    const int b  = blockIdx.x >> 9;
    const int c  = cg * 64 + cm;

    // combine predecessor chunk summaries (coalesced float4 loads)
    float h[4] = {0.f, 0.f, 0.f, 0.f};
    for (int k2 = 0; k2 < k; ++k2) {
        int gid2 = (((b * NCH + k2) << 4) + cg) * 256 + tid;
        float4 P4 = Pbuf[gid2];
        float4 L4 = Lbuf[gid2];
        h[0] = fmaf(P4.x, h[0], L4.x);
        h[1] = fmaf(P4.y, h[1], L4.y);
        h[2] = fmaf(P4.z, h[2], L4.z);
        h[3] = fmaf(P4.w, h[3], L4.w);
    }

    float a[4];
#pragma unroll
    for (int j = 0; j < 4; ++j)
        a[j] = -__expf(A_log[c * S_ + s4 * 4 + j]);

    const int tb = k * CHL;
    const float* dp = deltaT + ((size_t)b * C_ + c) * T_ + tb;
    const float* xp = xbaseT + ((size_t)b * C_ + c) * T_ + tb;
    const float* bp = BmT + ((size_t)(b * S_ + s4 * 4)) * T_ + tb;
    const float* cp = CmT + ((size_t)(b * S_ + s4 * 4)) * T_ + tb;
    float* hp = hyb + ((size_t)b * T_ + tb) * C_ + c;

    for (int t0 = 0; t0 < CHL; t0 += 4) {
        float4 d4 = *(const float4*)&dp[t0];
        float4 x4 = *(const float4*)&xp[t0];
        float dv[4] = {d4.x, d4.y, d4.z, d4.w};
        float xv[4] = {x4.x, x4.y, x4.z, x4.w};
        float bv[4][4], cv[4][4];
#pragma unroll
        for (int j = 0; j < 4; ++j) {
            float4 b4 = *(const float4*)&bp[(size_t)j * T_ + t0];
            float4 c4 = *(const float4*)&cp[(size_t)j * T_ + t0];
            bv[j][0] = b4.x; bv[j][1] = b4.y; bv[j][2] = b4.z; bv[j][3] = b4.w;
            cv[j][0] = c4.x; cv[j][1] = c4.y; cv[j][2] = c4.z; cv[j][3] = c4.w;
        }
#pragma unroll
        for (int q = 0; q < 4; ++q) {
            float u = dv[q] * xv[q];
#pragma unroll
            for (int j = 0; j < 4; ++j)
                h[j] = fmaf(__expf(dv[q] * a[j]), h[j], u * bv[j][q]);
            float y = h[0] * cv[0][q];
            y = fmaf(h[1], cv[1][q], y);
            y = fmaf(h[2], cv[2][q], y);
            y = fmaf(h[3], cv[3][q], y);
            y += __shfl_xor(y, 1, 64);
            y += __shfl_xor(y, 2, 64);
            if (s4 == 0) hp[(size_t)(t0 + q) * C_] = xv[q] + y;
        }
    }
}

// ---------------------------------------------------------------------------
// LayerNorm over C=1024, bf16 output.
// ---------------------------------------------------------------------------
__global__ __launch_bounds__(256) void layernorm_kernel(
    const float* __restrict__ in, const float* __restrict__ g,
    const float* __restrict__ beta, unsigned short* __restrict__ out)
{
    const int row = blockIdx.x;
    const float* rp = in + (size_t)row * C_;
    const int c = threadIdx.x * 4;
    float4 v = *(const float4*)&rp[c];
    float sum = v.x + v.y + v.z + v.w;
    float sq = v.x * v.x + v.y * v.y + v.z * v.z + v.w * v.w;
#pragma unroll
    for (int off = 1; off < 64; off <<= 1) {
        sum += __shfl_xor(sum, off, 64);
        sq += __shfl_xor(sq, off, 64);
    }
    __shared__ float sS[4], sQ[4];
    int wave = threadIdx.x >> 6, lane = threadIdx.x & 63;
    if (lane == 0) { sS[wave] = sum; sQ[wave] = sq; }
    __syncthreads();
    sum = sS[0] + sS[1] + sS[2] + sS[3];
    sq = sQ[0] + sQ[1] + sQ[2] + sQ[3];
    const float mu = sum * (1.f / C_);
    const float var = sq * (1.f / C_) - mu * mu;
    const float rstd = rsqrtf(var + 1e-5f);
    float4 gg = *(const float4*)&g[c];
    float4 bb = *(const float4*)&beta[c];
    ushort4v o;
    o.x = f2bf((v.x - mu) * rstd * gg.x + bb.x);
    o.y = f2bf((v.y - mu) * rstd * gg.y + bb.y);
    o.z = f2bf((v.z - mu) * rstd * gg.z + bb.z);
    o.w = f2bf((v.w - mu) * rstd * gg.w + bb.w);
    *(ushort4v*)&out[(size_t)row * C_ + c] = o;
}

// ---------------------------------------------------------------------------
// MFMA flash attention v2: BK=128, register-prefetch pipeline, ones-column
// row-sum trick, Q fragments in registers. q-tile pair (31-p, p).
// ---------------------------------------------------------------------------
#define BKT 128
#define KP  72
#define VP  136
__global__ __launch_bounds__(256) void attn_mfma(
    const unsigned short* __restrict__ Q, const unsigned short* __restrict__ K,
    const unsigned short* __restrict__ VT, const float* __restrict__ temp,
    unsigned short* __restrict__ out)
{
    __shared__ __align__(16) unsigned short Ks[BKT * KP];
    __shared__ __align__(16) unsigned short Vs[80 * VP];
    __shared__ __align__(16) unsigned short Ps[64 * VP];

    const int tid = threadIdx.x;
    const int w = tid >> 6, lane = tid & 63;
    const int lq = lane & 15, lg = lane >> 4;
    const int p  = blockIdx.x & 15;
    const int bh = blockIdx.x >> 4;
    const int b = bh >> 4, h = bh & 15;

    const float scale = softplus_f(temp[h]) * 0.125f;
    const unsigned short* Qp = Q + (size_t)bh * T_ * HD_;
    const unsigned short* Kp = K + (size_t)bh * T_ * HD_;
    const unsigned short* Vp = VT + (size_t)bh * HD_ * T_;

    {
        int r = 64 + (tid >> 4), o = (tid & 15) * 8;
        ushort8 ones = {0x3f80, 0x3f80, 0x3f80, 0x3f80,
                        0x3f80, 0x3f80, 0x3f80, 0x3f80};
        *(ushort8*)&Vs[r * VP + o] = ones;
    }

    ushort8 kreg[4], vreg[4];
    #define LOADKV(jtv)                                                        \
        do {                                                                   \
            int kb = (jtv) * BKT;                                              \
            _Pragma("unroll")                                                  \
            for (int q2 = 0; q2 < 4; ++q2) {                                   \
                int c = tid + q2 * 256;                                        \
                kreg[q2] = *(const ushort8*)&Kp[(size_t)(kb + (c >> 3)) * HD_  \
                                                + (c & 7) * 8];                \
                vreg[q2] = *(const ushort8*)&Vp[(size_t)(c >> 4) * T_ + kb     \
                                                + (c & 15) * 8];               \
            }                                                                  \
        } while (0)

    for (int half = 0; half < 2; ++half) {
        const int qi = half ? p : (31 - p);
        const int qbase = qi * 64;
        const int nT = (qbase + 64 + BKT - 1) / BKT;

        short8 qf[2];
#pragma unroll
        for (int s = 0; s < 2; ++s)
            qf[s] = *(const short8*)&Qp[(size_t)(qbase + w * 16 + lq) * HD_
                                        + s * 32 + lg * 8];
        LOADKV(0);

        float m_i[4];
        f32x4 o[5];
#pragma unroll
        for (int r = 0; r < 4; ++r) m_i[r] = -INFINITY;
#pragma unroll
        for (int j = 0; j < 5; ++j) o[j] = (f32x4){0.f, 0.f, 0.f, 0.f};

        for (int jt = 0; jt < nT; ++jt) {
            const int kbase = jt * BKT;
            const bool last = (jt == nT - 1);
            __syncthreads();
#pragma unroll
            for (int q2 = 0; q2 < 4; ++q2) {
                int c = tid + q2 * 256;
                *(ushort8*)&Ks[(c >> 3) * KP + (c & 7) * 8] = kreg[q2];
                *(ushort8*)&Vs[(c >> 4) * VP + (c & 15) * 8] = vreg[q2];
            }
            __syncthreads();
            if (jt + 1 < nT) LOADKV(jt + 1);

            f32x4 sacc[8];
#pragma unroll
            for (int j = 0; j < 8; ++j) sacc[j] = (f32x4){0.f, 0.f, 0.f, 0.f};
#pragma unroll
            for (int s = 0; s < 2; ++s) {
#pragma unroll
                for (int j = 0; j < 8; ++j) {
                    short8 kf = *(const short8*)&Ks[(j * 16 + lq) * KP
                                                    + s * 32 + lg * 8];
                    sacc[j] = __builtin_amdgcn_mfma_f32_16x16x32_bf16(
                        qf[s], kf, sacc[j], 0, 0, 0);
                }
            }

#pragma unroll
            for (int r = 0; r < 4; ++r) {
                int qrow = qbase + w * 16 + lg * 4 + r;
                float sv[8];
#pragma unroll
                for (int j = 0; j < 8; ++j) {
                    sv[j] = sacc[j][r] * scale;
                    if (last && (kbase + j * 16 + lq > qrow)) sv[j] = -INFINITY;
                }
                float mx = sv[0];
#pragma unroll
                for (int j = 1; j < 8; ++j) mx = fmaxf(mx, sv[j]);
                mx = fmaxf(mx, __shfl_xor(mx, 1, 64));
                mx = fmaxf(mx, __shfl_xor(mx, 2, 64));
                mx = fmaxf(mx, __shfl_xor(mx, 4, 64));
                mx = fmaxf(mx, __shfl_xor(mx, 8, 64));
                float mnew = fmaxf(m_i[r], mx);
                float alpha = __expf(m_i[r] - mnew);
                m_i[r] = mnew;
#pragma unroll
                for (int j = 0; j < 5; ++j) o[j][r] *= alpha;
#pragma unroll
                for (int j = 0; j < 8; ++j)
                    Ps[(w * 16 + lg * 4 + r) * VP + j * 16 + lq] =
                        f2bf(__expf(sv[j] - mnew));
            }

#pragma unroll
            for (int s2 = 0; s2 < 4; ++s2) {
                short8 pf = *(const short8*)&Ps[(w * 16 + lq) * VP
                                                + s2 * 32 + lg * 8];
#pragma unroll
                for (int j = 0; j < 5; ++j) {
                    short8 vf = *(const short8*)&Vs[(j * 16 + lq) * VP
                                                    + s2 * 32 + lg * 8];
                    o[j] = __builtin_amdgcn_mfma_f32_16x16x32_bf16(
                        pf, vf, o[j], 0, 0, 0);
                }
            }
        }

#pragma unroll
        for (int r = 0; r < 4; ++r) {
            float inv = 1.f / o[4][r];
            int qrow = qbase + w * 16 + lg * 4 + r;
#pragma unroll
            for (int j = 0; j < 4; ++j)
                out[((size_t)(b * T_ + qrow)) * C_ + h * 64 + j * 16 + lq] =
                    f2bf(o[j][r] * inv);
        }
    }
    #undef LOADKV
}

// ---------------------------------------------------------------------------
extern "C" void kernel_launch(void* const* d_in, const int* in_sizes, int n_in,
                              void* d_out, int out_size, void* d_ws, size_t ws_size,
                              hipStream_t stream)
{
    const float* x     = (const float*)d_in[0];
    const float* A_log = (const float*)d_in[1];
    const float* Wd    = (const float*)d_in[2];
    const float* bd    = (const float*)d_in[3];
    const float* WB    = (const float*)d_in[4];
    const float* WC    = (const float*)d_in[5];
    const float* Wq    = (const float*)d_in[6];
    const float* bq    = (const float*)d_in[7];
    const float* Wk    = (const float*)d_in[8];
    const float* bk    = (const float*)d_in[9];
    const float* Wv    = (const float*)d_in[10];
    const float* bv    = (const float*)d_in[11];
    const float* Wx    = (const float*)d_in[12];
    const float* bx    = (const float*)d_in[13];
    const float* Wo    = (const float*)d_in[14];
    const float* bo    = (const float*)d_in[15];
    const float* ln_g  = (const float*)d_in[16];
    const float* ln_b  = (const float*)d_in[17];
    const float* temp  = (const float*)d_in[18];

    char* wsb = (char*)d_ws;
    const size_t MB = 1024 * 1024;
    const size_t HMB = 512 * 1024;
    // Timeline-disjoint workspace map (identical to rounds 5-7 — verified):
    //  [0,8):      xb -> Pbuf/Lbuf (float4, 4 MB each) -> hybrid -> P1 [0,16)
    //  [8,12.5):   Astack + biasPD/biasQKV
    //  [12.5,18.5): WqkvT
    //  [18.5,20.5): deltaT head -> WoT (post-attention)
    //  [18.5,34.5): deltaT
    //  [20.5,28.5): Qb -> P0 [20.5,36.5)
    //  [28.5,36.5): Kb
    //  [34.5,50.5): xbaseT
    //  [36.5,44.5): VTb (over dead xbaseT)
    //  [44.5,52.5): attnO (over dead xbaseT tail / dead hyb head)
    //  [50.5,66.5): hyb
    //  [66.5,67):  BmT/CmT
    unsigned short* xb      = (unsigned short*)(wsb);
    float4* Pbuf            = (float4*)(wsb);
    float4* Lbuf            = (float4*)(wsb + 4 * MB);
    unsigned short* hybrid  = (unsigned short*)(wsb);
    float* P1               = (float*)(wsb);
    unsigned short* Astack  = (unsigned short*)(wsb + 8 * MB);
    float* biasPD           = (float*)(wsb + 8 * MB + (size_t)2176 * 2048);
    float* biasQKV          = biasPD + 2176;
    unsigned short* WqkvT   = (unsigned short*)(wsb + 12 * MB + HMB);
    unsigned short* WoT     = (unsigned short*)(wsb + 18 * MB + HMB);
    float* deltaT           = (float*)(wsb + 18 * MB + HMB);
    float* xbaseT           = (float*)(wsb + 34 * MB + HMB);
    float* hyb              = (float*)(wsb + 50 * MB + HMB);
    float* BmT              = (float*)(wsb + 66 * MB + HMB);
    float* CmT              = BmT + (size_t)B_ * S_ * T_;
    unsigned short* Qb      = (unsigned short*)(wsb + 20 * MB + HMB);
    unsigned short* Kb      = (unsigned short*)(wsb + 28 * MB + HMB);
    unsigned short* VTb     = (unsigned short*)(wsb + 36 * MB + HMB);
    unsigned short* attnO   = (unsigned short*)(wsb + 44 * MB + HMB);
    float* P0               = (float*)(wsb + 20 * MB + HMB);

    // ---- prep ----
    cast_bf16<<<4096, 256, 0, stream>>>(x, xb, (B_ * T_ * C_) / 4);
    wtrans_multi<<<dim3(32, 32, 5), 256, 0, stream>>>(Wx, Wd, Wq, Wk, Wv,
                                                      Astack, WqkvT);
    prep_misc<<<149, 256, 0, stream>>>(WB, WC, bx, bd, bq, bk, bv,
                                       Astack, biasPD, biasQKV);

    // ---- fused projection-T GEMM ----
    gemm_mfma<<<dim3(32, 17, 1), 256, 0, stream>>>(
        Astack, xb, biasPD, xbaseT, deltaT, BmT, CmT,
        2176, 4096, 1024, 1024, 1);

    // ---- chunk-parallel scan (FOLD=4) ----
    const int scanBlocks = B_ * NCH * (C_ / 64);   // 1024
    scan_partial<<<scanBlocks, 256, 0, stream>>>(xbaseT, deltaT, BmT, A_log,
                                                 Pbuf, Lbuf);
    scan_final<<<scanBlocks, 256, 0, stream>>>(xbaseT, deltaT, BmT, CmT, A_log,
                                               Pbuf, Lbuf, hyb);

    // ---- layernorm ----
    layernorm_kernel<<<B_ * T_, 256, 0, stream>>>(hyb, ln_g, ln_b, hybrid);

    // ---- fused QKV GEMM ----
    gemm_mfma<<<dim3(24, 32, 1), 256, 0, stream>>>(
        hybrid, WqkvT, biasQKV, Qb, Kb, VTb, nullptr,
        4096, 3072, 1024, 1024, 2);

    // ---- attention ----
    attn_mfma<<<B_ * H_ * 16, 256, 0, stream>>>(Qb, Kb, VTb, temp, attnO);

    // ---- Wo transpose + split-K GEMM + combine ----
    wtrans<<<dim3(32, 32), 256, 0, stream>>>(Wo, WoT);
    gemm_mfma<<<dim3(8, 32, 2), 256, 0, stream>>>(
        attnO, WoT, nullptr, P0, P1, nullptr, nullptr,
        4096, 1024, 512, 1024, 0);
    combine_out<<<4096, 256, 0, stream>>>(P0, P1, bo, (float*)d_out);
}

// Round 9
// 474.023 us; speedup vs baseline: 1.3105x; 1.0013x over previous
//
#include <hip/hip_runtime.h>
#include <math.h>

#define B_  2
#define T_  2048
#define C_  1024
#define H_  16
#define S_  16
#define HD_ 64
#define NCH 32
#define CHL 64   /* T_/NCH */

typedef short  short8  __attribute__((ext_vector_type(8)));
typedef unsigned short ushort8 __attribute__((ext_vector_type(8)));
typedef unsigned short ushort4v __attribute__((ext_vector_type(4)));
typedef float  f32x4   __attribute__((ext_vector_type(4)));

__device__ __forceinline__ float softplus_f(float v) {
    return fmaxf(v, 0.f) + log1pf(__expf(-fabsf(v)));
}

__device__ __forceinline__ unsigned short f2bf(float x) {
    unsigned u = __float_as_uint(x);
    u += 0x7fffu + ((u >> 16) & 1u);
    return (unsigned short)(u >> 16);
}

// ---------------------------------------------------------------------------
// cast fp32 -> bf16 (vectorized), n4 = n/4
// ---------------------------------------------------------------------------
__global__ __launch_bounds__(256) void cast_bf16(const float* __restrict__ in,
                                                 unsigned short* __restrict__ out,
                                                 int n4)
{
    int i = blockIdx.x * 256 + threadIdx.x;
    if (i >= n4) return;
    float4 v = ((const float4*)in)[i];
    ushort4v o = {f2bf(v.x), f2bf(v.y), f2bf(v.z), f2bf(v.w)};
    ((ushort4v*)out)[i] = o;
}

// ---------------------------------------------------------------------------
// transpose-cast: W (1024 x 1024 fp32) -> WT (1024 x 1024 bf16, transposed)
// ---------------------------------------------------------------------------
__device__ __forceinline__ void wtrans_body(const float* __restrict__ W,
                                            unsigned short* __restrict__ WT,
                                            int bx, int by, int tid)
{
    __shared__ float t[32][33];
    const int n0 = bx * 32, k0 = by * 32;
    const int tx = tid & 31, ty = tid >> 5;
#pragma unroll
    for (int p = 0; p < 4; ++p)
        t[ty + p * 8][tx] = W[(size_t)(k0 + ty + p * 8) * C_ + n0 + tx];
    __syncthreads();
#pragma unroll
    for (int p = 0; p < 4; ++p)
        WT[(size_t)(n0 + ty + p * 8) * C_ + k0 + tx] = f2bf(t[tx][ty + p * 8]);
}

__global__ __launch_bounds__(256) void wtrans(const float* __restrict__ W,
                                              unsigned short* __restrict__ WT)
{
    wtrans_body(W, WT, blockIdx.x, blockIdx.y, threadIdx.x);
}

// z: 0 Wx->Astack, 1 Wd->Astack+1024 rows, 2 Wq->Wqkv, 3 Wk->+1024, 4 Wv->+2048
__global__ __launch_bounds__(256) void wtrans_multi(
    const float* __restrict__ Wx, const float* __restrict__ Wd,
    const float* __restrict__ Wq, const float* __restrict__ Wk,
    const float* __restrict__ Wv,
    unsigned short* __restrict__ Astack, unsigned short* __restrict__ Wqkv)
{
    const float* src;
    unsigned short* dst;
    switch (blockIdx.z) {
        case 0: src = Wx; dst = Astack; break;
        case 1: src = Wd; dst = Astack + (size_t)1024 * 1024; break;
        case 2: src = Wq; dst = Wqkv; break;
        case 3: src = Wk; dst = Wqkv + (size_t)1024 * 1024; break;
        default: src = Wv; dst = Wqkv + (size_t)2048 * 1024; break;
    }
    wtrans_body(src, dst, blockIdx.x, blockIdx.y, threadIdx.x);
}

// ---------------------------------------------------------------------------
// misc prep: WB/WC transposed into Astack rows 2048..2079 + stacked biases
// ---------------------------------------------------------------------------
__global__ __launch_bounds__(256) void prep_misc(
    const float* __restrict__ WB, const float* __restrict__ WC,
    const float* __restrict__ bx, const float* __restrict__ bd,
    const float* __restrict__ bq, const float* __restrict__ bk,
    const float* __restrict__ bv,
    unsigned short* __restrict__ Astack, float* __restrict__ biasPD,
    float* __restrict__ biasQKV)
{
    int gid = blockIdx.x * 256 + threadIdx.x;
    if (gid < 32768) {
        int w = gid >> 14, rem = gid & 16383;
        int s = rem >> 10, k = rem & 1023;
        const float* src = w ? WC : WB;
        Astack[(size_t)(2048 + w * 16 + s) * 1024 + k] = f2bf(src[k * 16 + s]);
    } else {
        int id = gid - 32768;
        if (id < 2176) {
            biasPD[id] = id < 1024 ? bx[id] : (id < 2048 ? bd[id - 1024] : 0.f);
        } else {
            int id2 = id - 2176;
            if (id2 < 3072)
                biasQKV[id2] = id2 < 1024 ? bq[id2]
                             : (id2 < 2048 ? bk[id2 - 1024] : bv[id2 - 2048]);
        }
    }
}

// ---------------------------------------------------------------------------
// bf16 MFMA GEMM: acc = A(M x K) @ B(N x K)^T, both lda-strided K-major bf16.
// 128x128 tile, BK=32, 256 threads = 4 waves (2x2 of 64x64).
// Depth-2 register pipeline + double-buffered LDS + RELAXED barriers:
// "s_waitcnt lgkmcnt(0); s_barrier" keeps prefetch global loads in flight
// across the barrier (plain __syncthreads drains vmcnt(0) on gfx9 because
// vmcnt tracks stores too — that drain was the R8 MfmaUtil=12% stall).
// One barrier per 32-wide K-step; loads get ~2 bodies to land.
// K must be a multiple of 64 (1024 / 512 here).
// mode 0: split-K partial fp32; z=0 -> outv, z=1 -> out2 (no bias)
// mode 1: fused projT (outputs transposed (b,c,t) / (b,s,t))
// mode 2: fused QKV (Q/K heads, V transposed)
// ---------------------------------------------------------------------------
__global__ __launch_bounds__(256) void gemm_mfma(
    const unsigned short* __restrict__ A, const unsigned short* __restrict__ Bm,
    const float* __restrict__ bias,
    void* __restrict__ outv, void* __restrict__ out2,
    void* __restrict__ out3, void* __restrict__ out4,
    int M, int N, int K, int lda, int mode)
{
    __shared__ __align__(16) unsigned short As[2][4096];
    __shared__ __align__(16) unsigned short Bs[2][4096];

    const int tid = threadIdx.x;
    const int w = tid >> 6, lane = tid & 63;
    const int lq = lane & 15, lg = lane >> 4;
    const int wm = w >> 1, wn = w & 1;
    const int mBase = blockIdx.y * 128, nBase = blockIdx.x * 128;

    A  += (size_t)blockIdx.z * K;
    Bm += (size_t)blockIdx.z * K;

    const int c0 = tid, c1 = tid + 256;
    const int rA0 = ((c0 >> 6) << 4) + (c0 & 15), kO0 = ((c0 >> 4) & 3) << 3;
    const int rA1 = ((c1 >> 6) << 4) + (c1 & 15), kO1 = ((c1 >> 4) & 3) << 3;

    f32x4 acc[4][4];
#pragma unroll
    for (int i = 0; i < 4; ++i)
#pragma unroll
        for (int j = 0; j < 4; ++j) acc[i][j] = (f32x4){0.f, 0.f, 0.f, 0.f};

    const unsigned short* ga0 = A  + (size_t)(mBase + rA0) * lda + kO0;
    const unsigned short* ga1 = A  + (size_t)(mBase + rA1) * lda + kO1;
    const unsigned short* gb0 = Bm + (size_t)(nBase + rA0) * lda + kO0;
    const unsigned short* gb1 = Bm + (size_t)(nBase + rA1) * lda + kO1;

    ushort8 pA0, pA1, pB0, pB1;   // reg set P
    ushort8 qA0, qA1, qB0, qB1;   // reg set Q

    #define PREFS(SA0, SA1, SB0, SB1, k0v)                 \
        do {                                               \
            SA0 = *(const ushort8*)(ga0 + (k0v));          \
            SA1 = *(const ushort8*)(ga1 + (k0v));          \
            SB0 = *(const ushort8*)(gb0 + (k0v));          \
            SB1 = *(const ushort8*)(gb1 + (k0v));          \
        } while (0)
    #define STORES(SA0, SA1, SB0, SB1, bufv)               \
        do {                                               \
            *(ushort8*)&As[bufv][c0 * 8] = SA0;            \
            *(ushort8*)&As[bufv][c1 * 8] = SA1;            \
            *(ushort8*)&Bs[bufv][c0 * 8] = SB0;            \
            *(ushort8*)&Bs[bufv][c1 * 8] = SB1;            \
        } while (0)
    // LDS-only barrier: drain ds ops, leave global loads in flight.
    #define LBAR() asm volatile("s_waitcnt lgkmcnt(0)\n\ts_barrier" ::: "memory")
    #define COMPUTE(bufv)                                                       \
        do {                                                                    \
            short8 a[4], b[4];                                                  \
            _Pragma("unroll")                                                   \
            for (int i = 0; i < 4; ++i)                                         \
                a[i] = *(const short8*)&As[bufv][((wm * 4 + i) * 64 + lg * 16 + lq) * 8]; \
            _Pragma("unroll")                                                   \
            for (int j = 0; j < 4; ++j)                                         \
                b[j] = *(const short8*)&Bs[bufv][((wn * 4 + j) * 64 + lg * 16 + lq) * 8]; \
            _Pragma("unroll")                                                   \
            for (int i = 0; i < 4; ++i)                                         \
                _Pragma("unroll")                                               \
                for (int j = 0; j < 4; ++j)                                     \
                    acc[i][j] = __builtin_amdgcn_mfma_f32_16x16x32_bf16(        \
                        a[i], b[j], acc[i][j], 0, 0, 0);                        \
        } while (0)

    // preamble: tile0 -> LDS[0]; tile1 -> P; tile2 -> Q  (K >= 128 always)
    PREFS(pA0, pA1, pB0, pB1, 0);
    STORES(pA0, pA1, pB0, pB1, 0);
    PREFS(pA0, pA1, pB0, pB1, 32);
    PREFS(qA0, qA1, qB0, qB1, 64);
    LBAR();

    for (int k0 = 0; k0 < K; k0 += 64) {
        // body A: tile k0 in LDS[0]; P holds tile k0+32; Q loading k0+64
        if (k0 + 32 < K) STORES(pA0, pA1, pB0, pB1, 1);
        if (k0 + 96 < K) PREFS(pA0, pA1, pB0, pB1, k0 + 96);
        COMPUTE(0);
        LBAR();
        // body B: tile k0+32 in LDS[1]; Q holds tile k0+64; P loading k0+96
        if (k0 + 64 < K) STORES(qA0, qA1, qB0, qB1, 0);
        if (k0 + 128 < K) PREFS(qA0, qA1, qB0, qB1, k0 + 128);
        if (k0 + 32 < K) COMPUTE(1);
        LBAR();
    }
    #undef PREFS
    #undef STORES
    #undef LBAR
    #undef COMPUTE

    if (mode == 0) {
        float* O = blockIdx.z ? (float*)out2 : (float*)outv;
#pragma unroll
        for (int i = 0; i < 4; ++i) {
            int Rb = mBase + wm * 64 + i * 16 + lg * 4;
#pragma unroll
            for (int j = 0; j < 4; ++j) {
                int Cg = nBase + wn * 64 + j * 16 + lq;
#pragma unroll
                for (int r = 0; r < 4; ++r)
                    O[(size_t)(Rb + r) * N + Cg] = acc[i][j][r];
            }
        }
    } else if (mode == 1) {
        float* xbaseT = (float*)outv;
        float* deltaT = (float*)out2;
        float* BmT    = (float*)out3;
        float* CmT    = (float*)out4;
#pragma unroll
        for (int i = 0; i < 4; ++i) {
            int Rb = mBase + wm * 64 + i * 16 + lg * 4;
            if (Rb >= 2080) continue;
            float bb[4];
#pragma unroll
            for (int r = 0; r < 4; ++r) bb[r] = bias[Rb + r];
#pragma unroll
            for (int j = 0; j < 4; ++j) {
                int Cg = nBase + wn * 64 + j * 16 + lq;
                int b = Cg >> 11, t = Cg & (T_ - 1);
#pragma unroll
                for (int r = 0; r < 4; ++r) {
                    int R = Rb + r;
                    float v = acc[i][j][r] + bb[r];
                    if (Rb < 1024) {
                        xbaseT[((size_t)b * C_ + R) * T_ + t] = v;
                    } else if (Rb < 2048) {
                        deltaT[((size_t)b * C_ + (R - 1024)) * T_ + t] =
                            softplus_f(v);
                    } else if (Rb < 2064) {
                        BmT[((size_t)b * S_ + (R - 2048)) * T_ + t] = v;
                    } else {
                        CmT[((size_t)b * S_ + (R - 2064)) * T_ + t] = v;
                    }
                }
            }
        }
    } else { // mode 2: QKV
        unsigned short* Qb  = (unsigned short*)outv;
        unsigned short* Kb  = (unsigned short*)out2;
        unsigned short* VTb = (unsigned short*)out3;
#pragma unroll
        for (int j = 0; j < 4; ++j) {
            int Cg = nBase + wn * 64 + j * 16 + lq;
            int reg = Cg >> 10, c = Cg & 1023;
            int h = c >> 6, hd = c & 63;
            float bb = bias[Cg];
#pragma unroll
            for (int i = 0; i < 4; ++i) {
                int Rb = mBase + wm * 64 + i * 16 + lg * 4;
#pragma unroll
                for (int r = 0; r < 4; ++r) {
                    int R = Rb + r, b = R >> 11, t = R & (T_ - 1);
                    unsigned short o = f2bf(acc[i][j][r] + bb);
                    if (reg == 0)
                        Qb[(((size_t)(b * H_ + h) * T_ + t) * HD_) + hd] = o;
                    else if (reg == 1)
                        Kb[(((size_t)(b * H_ + h) * T_ + t) * HD_) + hd] = o;
                    else
                        VTb[(((size_t)(b * H_ + h) * HD_ + hd) * T_) + t] = o;
                }
            }
        }
    }
}

// ---------------------------------------------------------------------------
// combine split-K partials + bias -> d_out (fp32)
// ---------------------------------------------------------------------------
__global__ __launch_bounds__(256) void combine_out(
    const float* __restrict__ p0, const float* __restrict__ p1,
    const float* __restrict__ bo, float* __restrict__ out)
{
    int i = blockIdx.x * 256 + threadIdx.x;
    float4 a = ((const float4*)p0)[i];
    float4 b = ((const float4*)p1)[i];
    float4 bb = ((const float4*)bo)[i & 255];
    float4 o = {a.x + b.x + bb.x, a.y + b.y + bb.y,
                a.z + b.z + bb.z, a.w + b.w + bb.w};
    ((float4*)out)[i] = o;
}

// ---------------------------------------------------------------------------
// Chunked scan, FOLD=4 (verified R8 win).
// ---------------------------------------------------------------------------
__global__ __launch_bounds__(256) void scan_partial(
    const float* __restrict__ xbaseT, const float* __restrict__ deltaT,
    const float* __restrict__ BmT, const float* __restrict__ A_log,
    float4* __restrict__ Pbuf, float4* __restrict__ Lbuf)
{
    const int tid = threadIdx.x;
    const int s4 = tid & 3;
    const int cm = tid >> 2;
    const int cg = blockIdx.x & 15;
    const int k  = (blockIdx.x >> 4) & (NCH - 1);
    const int b  = blockIdx.x >> 9;
    const int c  = cg * 64 + cm;

    float a[4];
#pragma unroll
    for (int j = 0; j < 4; ++j)
        a[j] = -__expf(A_log[c * S_ + s4 * 4 + j]);

    const int tb = k * CHL;
    const float* dp = deltaT + ((size_t)b * C_ + c) * T_ + tb;
    const float* xp = xbaseT + ((size_t)b * C_ + c) * T_ + tb;
    const float* bp = BmT + ((size_t)(b * S_ + s4 * 4)) * T_ + tb;

    float L[4] = {0.f, 0.f, 0.f, 0.f};
    float sumd = 0.f;
    for (int t0 = 0; t0 < CHL; t0 += 4) {
        float4 d4 = *(const float4*)&dp[t0];
        float4 x4 = *(const float4*)&xp[t0];
        float dv[4] = {d4.x, d4.y, d4.z, d4.w};
        float xv[4] = {x4.x, x4.y, x4.z, x4.w};
        float bv[4][4];
#pragma unroll
        for (int j = 0; j < 4; ++j) {
            float4 b4 = *(const float4*)&bp[(size_t)j * T_ + t0];
            bv[j][0] = b4.x; bv[j][1] = b4.y; bv[j][2] = b4.z; bv[j][3] = b4.w;
        }
#pragma unroll
        for (int q = 0; q < 4; ++q) {
            float u = dv[q] * xv[q];
            sumd += dv[q];
#pragma unroll
            for (int j = 0; j < 4; ++j)
                L[j] = fmaf(__expf(dv[q] * a[j]), L[j], u * bv[j][q]);
        }
    }
    int gid = blockIdx.x * 256 + tid;
    float4 P4 = {__expf(a[0] * sumd), __expf(a[1] * sumd),
                 __expf(a[2] * sumd), __expf(a[3] * sumd)};
    float4 L4 = {L[0], L[1], L[2], L[3]};
    Pbuf[gid] = P4;
    Lbuf[gid] = L4;
}

__global__ __launch_bounds__(256) void scan_final(
    const float* __restrict__ xbaseT, const float* __restrict__ deltaT,
    const float* __restrict__ BmT, const float* __restrict__ CmT,
    const float* __restrict__ A_log, const float4* __restrict__ Pbuf,
    const float4* __restrict__ Lbuf, float* __restrict__ hyb)
{
    const int tid = threadIdx.x;
    const int s4 = tid & 3;
    const int cm = tid >> 2;
    const int cg = blockIdx.x & 15;
    const int k  = (blockIdx.x >> 4) & (NCH - 1);
    const int b  = blockIdx.x >> 9;
    const int c  = cg * 64 + cm;

    float h[4] = {0.f, 0.f, 0.f, 0.f};
    for (int k2 = 0; k2 < k; ++k2) {
        int gid2 = (((b * NCH + k2) << 4) + cg) * 256 + tid;
        float4 P4 = Pbuf[gid2];
        float4 L4 = Lbuf[gid2];
        h[0] = fmaf(P4.x, h[0], L4.x);
        h[1] = fmaf(P4.y, h[1], L4.y);
        h[2] = fmaf(P4.z, h[2], L4.z);
        h[3] = fmaf(P4.w, h[3], L4.w);
    }

    float a[4];
#pragma unroll
    for (int j = 0; j < 4; ++j)
        a[j] = -__expf(A_log[c * S_ + s4 * 4 + j]);

    const int tb = k * CHL;
    const float* dp = deltaT + ((size_t)b * C_ + c) * T_ + tb;
    const float* xp = xbaseT + ((size_t)b * C_ + c) * T_ + tb;
    const float* bp = BmT + ((size_t)(b * S_ + s4 * 4)) * T_ + tb;
    const float* cp = CmT + ((size_t)(b * S_ + s4 * 4)) * T_ + tb;
    float* hp = hyb + ((size_t)b * T_ + tb) * C_ + c;

    for (int t0 = 0; t0 < CHL; t0 += 4) {
        float4 d4 = *(const float4*)&dp[t0];
        float4 x4 = *(const float4*)&xp[t0];
        float dv[4] = {d4.x, d4.y, d4.z, d4.w};
        float xv[4] = {x4.x, x4.y, x4.z, x4.w};
        float bv[4][4], cv[4][4];
#pragma unroll
        for (int j = 0; j < 4; ++j) {
            float4 b4 = *(const float4*)&bp[(size_t)j * T_ + t0];
            float4 c4 = *(const float4*)&cp[(size_t)j * T_ + t0];
            bv[j][0] = b4.x; bv[j][1] = b4.y; bv[j][2] = b4.z; bv[j][3] = b4.w;
            cv[j][0] = c4.x; cv[j][1] = c4.y; cv[j][2] = c4.z; cv[j][3] = c4.w;
        }
#pragma unroll
        for (int q = 0; q < 4; ++q) {
            float u = dv[q] * xv[q];
#pragma unroll
            for (int j = 0; j < 4; ++j)
                h[j] = fmaf(__expf(dv[q] * a[j]), h[j], u * bv[j][q]);
            float y = h[0] * cv[0][q];
            y = fmaf(h[1], cv[1][q], y);
            y = fmaf(h[2], cv[2][q], y);
            y = fmaf(h[3], cv[3][q], y);
            y += __shfl_xor(y, 1, 64);
            y += __shfl_xor(y, 2, 64);
            if (s4 == 0) hp[(size_t)(t0 + q) * C_] = xv[q] + y;
        }
    }
}

// ---------------------------------------------------------------------------
// LayerNorm over C=1024, bf16 output.
// ---------------------------------------------------------------------------
__global__ __launch_bounds__(256) void layernorm_kernel(
    const float* __restrict__ in, const float* __restrict__ g,
    const float* __restrict__ beta, unsigned short* __restrict__ out)
{
    const int row = blockIdx.x;
    const float* rp = in + (size_t)row * C_;
    const int c = threadIdx.x * 4;
    float4 v = *(const float4*)&rp[c];
    float sum = v.x + v.y + v.z + v.w;
    float sq = v.x * v.x + v.y * v.y + v.z * v.z + v.w * v.w;
#pragma unroll
    for (int off = 1; off < 64; off <<= 1) {
        sum += __shfl_xor(sum, off, 64);
        sq += __shfl_xor(sq, off, 64);
    }
    __shared__ float sS[4], sQ[4];
    int wave = threadIdx.x >> 6, lane = threadIdx.x & 63;
    if (lane == 0) { sS[wave] = sum; sQ[wave] = sq; }
    __syncthreads();
    sum = sS[0] + sS[1] + sS[2] + sS[3];
    sq = sQ[0] + sQ[1] + sQ[2] + sQ[3];
    const float mu = sum * (1.f / C_);
    const float var = sq * (1.f / C_) - mu * mu;
    const float rstd = rsqrtf(var + 1e-5f);
    float4 gg = *(const float4*)&g[c];
    float4 bb = *(const float4*)&beta[c];
    ushort4v o;
    o.x = f2bf((v.x - mu) * rstd * gg.x + bb.x);
    o.y = f2bf((v.y - mu) * rstd * gg.y + bb.y);
    o.z = f2bf((v.z - mu) * rstd * gg.z + bb.z);
    o.w = f2bf((v.w - mu) * rstd * gg.w + bb.w);
    *(ushort4v*)&out[(size_t)row * C_ + c] = o;
}

// ---------------------------------------------------------------------------
// MFMA flash attention v2: BK=128, register-prefetch pipeline, ones-column
// row-sum trick, Q fragments in registers. q-tile pair (31-p, p).
// ---------------------------------------------------------------------------
#define BKT 128
#define KP  72
#define VP  136
__global__ __launch_bounds__(256) void attn_mfma(
    const unsigned short* __restrict__ Q, const unsigned short* __restrict__ K,
    const unsigned short* __restrict__ VT, const float* __restrict__ temp,
    unsigned short* __restrict__ out)
{
    __shared__ __align__(16) unsigned short Ks[BKT * KP];
    __shared__ __align__(16) unsigned short Vs[80 * VP];
    __shared__ __align__(16) unsigned short Ps[64 * VP];

    const int tid = threadIdx.x;
    const int w = tid >> 6, lane = tid & 63;
    const int lq = lane & 15, lg = lane >> 4;
    const int p  = blockIdx.x & 15;
    const int bh = blockIdx.x >> 4;
    const int b = bh >> 4, h = bh & 15;

    const float scale = softplus_f(temp[h]) * 0.125f;
    const unsigned short* Qp = Q + (size_t)bh * T_ * HD_;
    const unsigned short* Kp = K + (size_t)bh * T_ * HD_;
    const unsigned short* Vp = VT + (size_t)bh * HD_ * T_;

    {
        int r = 64 + (tid >> 4), o = (tid & 15) * 8;
        ushort8 ones = {0x3f80, 0x3f80, 0x3f80, 0x3f80,
                        0x3f80, 0x3f80, 0x3f80, 0x3f80};
        *(ushort8*)&Vs[r * VP + o] = ones;
    }

    ushort8 kreg[4], vreg[4];
    #define LOADKV(jtv)                                                        \
        do {                                                                   \
            int kb = (jtv) * BKT;                                              \
            _Pragma("unroll")                                                  \
            for (int q2 = 0; q2 < 4; ++q2) {                                   \
                int c = tid + q2 * 256;                                        \
                kreg[q2] = *(const ushort8*)&Kp[(size_t)(kb + (c >> 3)) * HD_  \
                                                + (c & 7) * 8];                \
                vreg[q2] = *(const ushort8*)&Vp[(size_t)(c >> 4) * T_ + kb     \
                                                + (c & 15) * 8];               \
            }                                                                  \
        } while (0)

    for (int half = 0; half < 2; ++half) {
        const int qi = half ? p : (31 - p);
        const int qbase = qi * 64;
        const int nT = (qbase + 64 + BKT - 1) / BKT;

        short8 qf[2];
#pragma unroll
        for (int s = 0; s < 2; ++s)
            qf[s] = *(const short8*)&Qp[(size_t)(qbase + w * 16 + lq) * HD_
                                        + s * 32 + lg * 8];
        LOADKV(0);

        float m_i[4];
        f32x4 o[5];
#pragma unroll
        for (int r = 0; r < 4; ++r) m_i[r] = -INFINITY;
#pragma unroll
        for (int j = 0; j < 5; ++j) o[j] = (f32x4){0.f, 0.f, 0.f, 0.f};

        for (int jt = 0; jt < nT; ++jt) {
            const int kbase = jt * BKT;
            const bool last = (jt == nT - 1);
            __syncthreads();
#pragma unroll
            for (int q2 = 0; q2 < 4; ++q2) {
                int c = tid + q2 * 256;
                *(ushort8*)&Ks[(c >> 3) * KP + (c & 7) * 8] = kreg[q2];
                *(ushort8*)&Vs[(c >> 4) * VP + (c & 15) * 8] = vreg[q2];
            }
            __syncthreads();
            if (jt + 1 < nT) LOADKV(jt + 1);

            f32x4 sacc[8];
#pragma unroll
            for (int j = 0; j < 8; ++j) sacc[j] = (f32x4){0.f, 0.f, 0.f, 0.f};
#pragma unroll
            for (int s = 0; s < 2; ++s) {
#pragma unroll
                for (int j = 0; j < 8; ++j) {
                    short8 kf = *(const short8*)&Ks[(j * 16 + lq) * KP
                                                    + s * 32 + lg * 8];
                    sacc[j] = __builtin_amdgcn_mfma_f32_16x16x32_bf16(
                        qf[s], kf, sacc[j], 0, 0, 0);
                }
            }

#pragma unroll
            for (int r = 0; r < 4; ++r) {
                int qrow = qbase + w * 16 + lg * 4 + r;
                float sv[8];
#pragma unroll
                for (int j = 0; j < 8; ++j) {
                    sv[j] = sacc[j][r] * scale;
                    if (last && (kbase + j * 16 + lq > qrow)) sv[j] = -INFINITY;
                }
                float mx = sv[0];
#pragma unroll
                for (int j = 1; j < 8; ++j) mx = fmaxf(mx, sv[j]);
                mx = fmaxf(mx, __shfl_xor(mx, 1, 64));
                mx = fmaxf(mx, __shfl_xor(mx, 2, 64));
                mx = fmaxf(mx, __shfl_xor(mx, 4, 64));
                mx = fmaxf(mx, __shfl_xor(mx, 8, 64));
                float mnew = fmaxf(m_i[r], mx);
                float alpha = __expf(m_i[r] - mnew);
                m_i[r] = mnew;
#pragma unroll
                for (int j = 0; j < 5; ++j) o[j][r] *= alpha;
#pragma unroll
                for (int j = 0; j < 8; ++j)
                    Ps[(w * 16 + lg * 4 + r) * VP + j * 16 + lq] =
                        f2bf(__expf(sv[j] - mnew));
            }

#pragma unroll
            for (int s2 = 0; s2 < 4; ++s2) {
                short8 pf = *(const short8*)&Ps[(w * 16 + lq) * VP
                                                + s2 * 32 + lg * 8];
#pragma unroll
                for (int j = 0; j < 5; ++j) {
                    short8 vf = *(const short8*)&Vs[(j * 16 + lq) * VP
                                                    + s2 * 32 + lg * 8];
                    o[j] = __builtin_amdgcn_mfma_f32_16x16x32_bf16(
                        pf, vf, o[j], 0, 0, 0);
                }
            }
        }

#pragma unroll
        for (int r = 0; r < 4; ++r) {
            float inv = 1.f / o[4][r];
            int qrow = qbase + w * 16 + lg * 4 + r;
#pragma unroll
            for (int j = 0; j < 4; ++j)
                out[((size_t)(b * T_ + qrow)) * C_ + h * 64 + j * 16 + lq] =
                    f2bf(o[j][r] * inv);
        }
    }
    #undef LOADKV
}

// ---------------------------------------------------------------------------
extern "C" void kernel_launch(void* const* d_in, const int* in_sizes, int n_in,
                              void* d_out, int out_size, void* d_ws, size_t ws_size,
                              hipStream_t stream)
{
    const float* x     = (const float*)d_in[0];
    const float* A_log = (const float*)d_in[1];
    const float* Wd    = (const float*)d_in[2];
    const float* bd    = (const float*)d_in[3];
    const float* WB    = (const float*)d_in[4];
    const float* WC    = (const float*)d_in[5];
    const float* Wq    = (const float*)d_in[6];
    const float* bq    = (const float*)d_in[7];
    const float* Wk    = (const float*)d_in[8];
    const float* bk    = (const float*)d_in[9];
    const float* Wv    = (const float*)d_in[10];
    const float* bv    = (const float*)d_in[11];
    const float* Wx    = (const float*)d_in[12];
    const float* bx    = (const float*)d_in[13];
    const float* Wo    = (const float*)d_in[14];
    const float* bo    = (const float*)d_in[15];
    const float* ln_g  = (const float*)d_in[16];
    const float* ln_b  = (const float*)d_in[17];
    const float* temp  = (const float*)d_in[18];

    char* wsb = (char*)d_ws;
    const size_t MB = 1024 * 1024;
    const size_t HMB = 512 * 1024;
    // Timeline-disjoint workspace map (identical to rounds 5-8 — verified):
    //  [0,8):      xb -> Pbuf/Lbuf (float4, 4 MB each) -> hybrid -> P1 [0,16)
    //  [8,12.5):   Astack + biasPD/biasQKV
    //  [12.5,18.5): WqkvT
    //  [18.5,20.5): deltaT head -> WoT (post-attention)
    //  [18.5,34.5): deltaT
    //  [20.5,28.5): Qb -> P0 [20.5,36.5)
    //  [28.5,36.5): Kb
    //  [34.5,50.5): xbaseT
    //  [36.5,44.5): VTb (over dead xbaseT)
    //  [44.5,52.5): attnO (over dead xbaseT tail / dead hyb head)
    //  [50.5,66.5): hyb
    //  [66.5,67):  BmT/CmT
    unsigned short* xb      = (unsigned short*)(wsb);
    float4* Pbuf            = (float4*)(wsb);
    float4* Lbuf            = (float4*)(wsb + 4 * MB);
    unsigned short* hybrid  = (unsigned short*)(wsb);
    float* P1               = (float*)(wsb);
    unsigned short* Astack  = (unsigned short*)(wsb + 8 * MB);
    float* biasPD           = (float*)(wsb + 8 * MB + (size_t)2176 * 2048);
    float* biasQKV          = biasPD + 2176;
    unsigned short* WqkvT   = (unsigned short*)(wsb + 12 * MB + HMB);
    unsigned short* WoT     = (unsigned short*)(wsb + 18 * MB + HMB);
    float* deltaT           = (float*)(wsb + 18 * MB + HMB);
    float* xbaseT           = (float*)(wsb + 34 * MB + HMB);
    float* hyb              = (float*)(wsb + 50 * MB + HMB);
    float* BmT              = (float*)(wsb + 66 * MB + HMB);
    float* CmT              = BmT + (size_t)B_ * S_ * T_;
    unsigned short* Qb      = (unsigned short*)(wsb + 20 * MB + HMB);
    unsigned short* Kb      = (unsigned short*)(wsb + 28 * MB + HMB);
    unsigned short* VTb     = (unsigned short*)(wsb + 36 * MB + HMB);
    unsigned short* attnO   = (unsigned short*)(wsb + 44 * MB + HMB);
    float* P0               = (float*)(wsb + 20 * MB + HMB);

    // ---- prep ----
    cast_bf16<<<4096, 256, 0, stream>>>(x, xb, (B_ * T_ * C_) / 4);
    wtrans_multi<<<dim3(32, 32, 5), 256, 0, stream>>>(Wx, Wd, Wq, Wk, Wv,
                                                      Astack, WqkvT);
    prep_misc<<<149, 256, 0, stream>>>(WB, WC, bx, bd, bq, bk, bv,
                                       Astack, biasPD, biasQKV);

    // ---- fused projection-T GEMM ----
    gemm_mfma<<<dim3(32, 17, 1), 256, 0, stream>>>(
        Astack, xb, biasPD, xbaseT, deltaT, BmT, CmT,
        2176, 4096, 1024, 1024, 1);

    // ---- chunk-parallel scan (FOLD=4) ----
    const int scanBlocks = B_ * NCH * (C_ / 64);   // 1024
    scan_partial<<<scanBlocks, 256, 0, stream>>>(xbaseT, deltaT, BmT, A_log,
                                                 Pbuf, Lbuf);
    scan_final<<<scanBlocks, 256, 0, stream>>>(xbaseT, deltaT, BmT, CmT, A_log,
                                               Pbuf, Lbuf, hyb);

    // ---- layernorm ----
    layernorm_kernel<<<B_ * T_, 256, 0, stream>>>(hyb, ln_g, ln_b, hybrid);

    // ---- fused QKV GEMM ----
    gemm_mfma<<<dim3(24, 32, 1), 256, 0, stream>>>(
        hybrid, WqkvT, biasQKV, Qb, Kb, VTb, nullptr,
        4096, 3072, 1024, 1024, 2);

    // ---- attention ----
    attn_mfma<<<B_ * H_ * 16, 256, 0, stream>>>(Qb, Kb, VTb, temp, attnO);

    // ---- Wo transpose + split-K GEMM + combine ----
    wtrans<<<dim3(32, 32), 256, 0, stream>>>(Wo, WoT);
    gemm_mfma<<<dim3(8, 32, 2), 256, 0, stream>>>(
        attnO, WoT, nullptr, P0, P1, nullptr, nullptr,
        4096, 1024, 512, 1024, 0);
    combine_out<<<4096, 256, 0, stream>>>(P0, P1, bo, (float*)d_out);
}